// Round 1
// baseline (1791.618 us; speedup 1.0000x reference)
//
#include <hip/hip_runtime.h>

#define NN 50000
#define EE 800000
#define BB 64

// ---------------- elementwise mask: xm = x * (x != -1) ----------------
__global__ void mask_kernel(const float* __restrict__ x, float* __restrict__ xm, int n4){
  int i = blockIdx.x*blockDim.x + threadIdx.x;
  if (i >= n4) return;
  float4 v = ((const float4*)x)[i];
  v.x = (v.x==-1.0f)?0.f:v.x;
  v.y = (v.y==-1.0f)?0.f:v.y;
  v.z = (v.z==-1.0f)?0.f:v.z;
  v.w = (v.w==-1.0f)?0.f:v.w;
  ((float4*)xm)[i] = v;
}

// ---------------- CSR build ----------------
__global__ void count_kernel(const int* __restrict__ dst, int* __restrict__ cnt, int e){
  int i = blockIdx.x*blockDim.x + threadIdx.x;
  if (i < e) atomicAdd(&cnt[dst[i]], 1);
}

__global__ __launch_bounds__(1024)
void scan_kernel(const int* __restrict__ cnt, int* __restrict__ ptr, int* __restrict__ cur, int n){
  __shared__ int s[1024];
  int t = threadIdx.x;
  const int chunk = (n + 1023)/1024;
  int i0 = t*chunk;
  int i1 = i0 + chunk; if (i1 > n) i1 = n;
  int local = 0;
  for (int i=i0;i<i1;i++) local += cnt[i];
  s[t] = local; __syncthreads();
  for (int off=1; off<1024; off<<=1){
    int v = (t>=off) ? s[t-off] : 0;
    __syncthreads();
    s[t] += v;
    __syncthreads();
  }
  int run = s[t] - local;   // exclusive base
  for (int i=i0;i<i1;i++){ ptr[i]=run; cur[i]=run; run += cnt[i]; }
  if (t==1023) ptr[n] = s[1023];
}

__global__ void fill_kernel(const int* __restrict__ dst, int* __restrict__ cur, int* __restrict__ slot, int e){
  int i = blockIdx.x*blockDim.x + threadIdx.x;
  if (i < e){ int p = atomicAdd(&cur[dst[i]], 1); slot[p] = i; }
}

// ---------------- CSR gather: out[n] = sum_{e: dst=n} ew[e]*H[src[e]] ----------------
template<int F>
__global__ __launch_bounds__(256)
void gather_kernel(const float* __restrict__ H, int ldh,
                   const int* __restrict__ ptr, const int* __restrict__ slot,
                   const int* __restrict__ src, const float* __restrict__ ew,
                   float* __restrict__ out, int ldo, int n){
  const int L = F/4;                  // lanes per node
  int gt = blockIdx.x*blockDim.x + threadIdx.x;
  int node = gt / L;
  int lane = gt % L;
  if (node >= n) return;
  int lo = ptr[node], hi = ptr[node+1];
  float4 acc = make_float4(0.f,0.f,0.f,0.f);
  for (int p=lo; p<hi; ++p){
    int e = slot[p];
    int s = src[e];
    float wgt = ew[e];
    float4 v = *(const float4*)(H + (size_t)s*ldh + lane*4);
    acc.x += wgt*v.x; acc.y += wgt*v.y; acc.z += wgt*v.z; acc.w += wgt*v.w;
  }
  *(float4*)(out + (size_t)node*ldo + lane*4) = acc;
}

// ---------------- fused dual GEMM: out = relu?(A@W1 + R@W2 + b1 (+ b2)) ----------------
// tile 64 rows x 128 cols per block, 256 threads, BK=32, fp32 VALU
template<int K, bool RELU>
__global__ __launch_bounds__(256)
void gemm_kernel(const float* __restrict__ A, int lda,
                 const float* __restrict__ W1,
                 const float* __restrict__ R, int ldr,
                 const float* __restrict__ W2, int ldw,
                 const float* __restrict__ b1, const float* __restrict__ b2,
                 float* __restrict__ out, int ldo, int rows){
  __shared__ float As[64][32];
  __shared__ float Ws[32][128];
  const int tid = threadIdx.x;
  const int row0 = blockIdx.x*64;
  const int colbase = blockIdx.y*128;
  const int tx = tid & 31, ty = tid >> 5;
  float4 acc[8];
  #pragma unroll
  for (int i=0;i<8;i++) acc[i] = make_float4(0.f,0.f,0.f,0.f);

  #pragma unroll 1
  for (int pass=0; pass<2; ++pass){
    const float* Ap = pass ? R  : A;
    const int    ld = pass ? ldr : lda;
    const float* Wp = pass ? W2 : W1;
    #pragma unroll 1
    for (int k0=0; k0<K; k0+=32){
      __syncthreads();
      {
        int r  = tid >> 3;           // 0..31
        int kv = (tid & 7) << 2;     // 0..28
        #pragma unroll
        for (int rr = r; rr < 64; rr += 32){
          int gr = row0 + rr;
          float4 v = make_float4(0.f,0.f,0.f,0.f);
          if (gr < rows) v = *(const float4*)(Ap + (size_t)gr*ld + k0 + kv);
          *(float4*)&As[rr][kv] = v;
        }
        int c4 = (tid & 31) << 2;
        int kr = tid >> 5;
        #pragma unroll
        for (int kk = kr; kk < 32; kk += 8){
          *(float4*)&Ws[kk][c4] = *(const float4*)(Wp + (size_t)(k0+kk)*ldw + colbase + c4);
        }
      }
      __syncthreads();
      #pragma unroll
      for (int kk=0; kk<32; kk+=4){
        float4 w0 = *(float4*)&Ws[kk+0][tx<<2];
        float4 w1 = *(float4*)&Ws[kk+1][tx<<2];
        float4 w2 = *(float4*)&Ws[kk+2][tx<<2];
        float4 w3 = *(float4*)&Ws[kk+3][tx<<2];
        #pragma unroll
        for (int i=0;i<8;i++){
          float4 a = *(float4*)&As[ty*8+i][kk];
          acc[i].x += a.x*w0.x + a.y*w1.x + a.z*w2.x + a.w*w3.x;
          acc[i].y += a.x*w0.y + a.y*w1.y + a.z*w2.y + a.w*w3.y;
          acc[i].z += a.x*w0.z + a.y*w1.z + a.z*w2.z + a.w*w3.z;
          acc[i].w += a.x*w0.w + a.y*w1.w + a.z*w2.w + a.w*w3.w;
        }
      }
    }
  }
  float4 bv = *(const float4*)(b1 + colbase + (tx<<2));
  if (b2){
    float4 b2v = *(const float4*)(b2 + colbase + (tx<<2));
    bv.x += b2v.x; bv.y += b2v.y; bv.z += b2v.z; bv.w += b2v.w;
  }
  #pragma unroll
  for (int i=0;i<8;i++){
    int gr = row0 + ty*8 + i;
    if (gr < rows){
      float4 o = acc[i];
      o.x += bv.x; o.y += bv.y; o.z += bv.z; o.w += bv.w;
      if (RELU){
        o.x = fmaxf(o.x,0.f); o.y = fmaxf(o.y,0.f);
        o.z = fmaxf(o.z,0.f); o.w = fmaxf(o.w,0.f);
      }
      *(float4*)(out + (size_t)gr*ldo + colbase + (tx<<2)) = o;
    }
  }
}

// ---------------- Wsum = c1_Wroot + skip_W ----------------
__global__ void addw_kernel(const float* __restrict__ a, const float* __restrict__ b,
                            float* __restrict__ o, int n4){
  int i = blockIdx.x*blockDim.x + threadIdx.x;
  if (i < n4){
    float4 xv = ((const float4*)a)[i], yv = ((const float4*)b)[i];
    xv.x += yv.x; xv.y += yv.y; xv.z += yv.z; xv.w += yv.w;
    ((float4*)o)[i] = xv;
  }
}

// ---------------- mean pool per batch (batch sorted) ----------------
__device__ __forceinline__ int lower_bound_i(const int* __restrict__ arr, int n, int v){
  int lo=0, hi=n;
  while (lo < hi){ int mid=(lo+hi)>>1; if (arr[mid] < v) lo=mid+1; else hi=mid; }
  return lo;
}

__global__ __launch_bounds__(256)
void pool_kernel(const float* __restrict__ xc2, const int* __restrict__ batch,
                 float* __restrict__ emb, int n){
  int b = blockIdx.x;
  int lo = lower_bound_i(batch, n, b);
  int hi = lower_bound_i(batch, n, b+1);
  float s = 0.f;
  for (int r=lo; r<hi; ++r) s += xc2[(size_t)r*256 + threadIdx.x];
  float c = (float)(hi - lo);
  emb[b*256 + threadIdx.x] = s / fmaxf(c, 1.0f);
}

// ---------------- sequence MLP ----------------
__global__ __launch_bounds__(256)
void seq_kernel(const float* __restrict__ seq,
                const float* __restrict__ W1, const float* __restrict__ b1,
                const float* __restrict__ W2, const float* __restrict__ b2,
                float* __restrict__ s2){
  __shared__ float sin_[256], s1[256];
  int b = blockIdx.x, t = threadIdx.x;
  sin_[t] = seq[b*256 + t];
  __syncthreads();
  float a = b1[t];
  for (int k=0;k<256;k++) a += sin_[k]*W1[k*256 + t];
  s1[t] = fmaxf(a, 0.f);
  __syncthreads();
  if (t < 128){
    float a2 = b2[t];
    for (int k=0;k<256;k++) a2 += s1[k]*W2[k*128 + t];
    s2[b*128 + t] = fmaxf(a2, 0.f);
  }
}

// ---------------- fused head: concat + fcc + cls + log_softmax ----------------
__global__ __launch_bounds__(256)
void head_kernel(const float* __restrict__ emb, const float* __restrict__ s2,
                 const float* __restrict__ fccW, const float* __restrict__ fccb,
                 const float* __restrict__ clsW, const float* __restrict__ clsb,
                 float* __restrict__ out){
  __shared__ float h[384], h2[256], lg[16];
  __shared__ float mred, lred;
  int b = blockIdx.x, t = threadIdx.x;
  h[t] = emb[b*256 + t];
  if (t < 128) h[256 + t] = s2[b*128 + t];
  __syncthreads();
  float a = fccb[t];
  for (int k=0;k<384;k++) a += h[k]*fccW[k*256 + t];
  h2[t] = fmaxf(a, 0.f);
  __syncthreads();
  if (t < 16){
    float a2 = clsb[t];
    for (int k=0;k<256;k++) a2 += h2[k]*clsW[k*16 + t];
    lg[t] = a2;
  }
  __syncthreads();
  if (t == 0){
    float m = lg[0];
    for (int i=1;i<16;i++) m = fmaxf(m, lg[i]);
    float s = 0.f;
    for (int i=0;i<16;i++) s += expf(lg[i]-m);
    mred = m; lred = logf(s);
  }
  __syncthreads();
  if (t < 16) out[b*16 + t] = lg[t] - mred - lred;
}

extern "C" void kernel_launch(void* const* d_in, const int* in_sizes, int n_in,
                              void* d_out, int out_size, void* d_ws, size_t ws_size,
                              hipStream_t stream){
  const float* x      = (const float*)d_in[0];
  const int*   ei     = (const int*)  d_in[1];
  const float* ea     = (const float*)d_in[2];
  const int*   batch  = (const int*)  d_in[3];
  const float* dx     = (const float*)d_in[4];
  const int*   dei    = (const int*)  d_in[5];
  const float* dea    = (const float*)d_in[6];
  const float* seq    = (const float*)d_in[7];
  const float* g1_Wr  = (const float*)d_in[8];
  const float* g1_br  = (const float*)d_in[9];
  const float* g1_Wrt = (const float*)d_in[10];
  const float* g2_Wr  = (const float*)d_in[11];
  const float* g2_br  = (const float*)d_in[12];
  const float* g2_Wrt = (const float*)d_in[13];
  const float* d1_Wr  = (const float*)d_in[14];
  const float* d1_br  = (const float*)d_in[15];
  const float* d1_Wrt = (const float*)d_in[16];
  const float* c1_Wr  = (const float*)d_in[17];
  const float* c1_br  = (const float*)d_in[18];
  const float* c1_Wrt = (const float*)d_in[19];
  const float* skip_W = (const float*)d_in[20];
  const float* skip_b = (const float*)d_in[21];
  const float* fc1_W  = (const float*)d_in[22];
  const float* fc1_b  = (const float*)d_in[23];
  const float* fc2_W  = (const float*)d_in[24];
  const float* fc2_b  = (const float*)d_in[25];
  const float* fcc_W  = (const float*)d_in[26];
  const float* fcc_b  = (const float*)d_in[27];
  const float* cls_W  = (const float*)d_in[28];
  const float* cls_b  = (const float*)d_in[29];
  float* out = (float*)d_out;

  char* wp = (char*)d_ws;
  auto alloc = [&](size_t bytes)->char*{
    char* p = wp; wp += (bytes + 255) & ~(size_t)255; return p;
  };
  float* XM   = (float*)alloc((size_t)NN*128*4);
  float* F1   = (float*)alloc((size_t)NN*128*4);
  float* AGG  = (float*)alloc((size_t)NN*256*4);
  float* XC   = (float*)alloc((size_t)NN*256*4);
  float* XC2  = (float*)alloc((size_t)NN*256*4);
  float* WSUM = (float*)alloc((size_t)256*256*4);
  int*   PTR1 = (int*)alloc((size_t)(NN+1)*4);
  int*   SLOT1= (int*)alloc((size_t)EE*4);
  int*   PTR2 = (int*)alloc((size_t)(NN+1)*4);
  int*   SLOT2= (int*)alloc((size_t)EE*4);
  int*   CNT  = (int*)alloc((size_t)NN*4);
  int*   CUR  = (int*)alloc((size_t)NN*4);
  float* EMB  = (float*)alloc((size_t)BB*256*4);
  float* S2B  = (float*)alloc((size_t)BB*128*4);

  const int* src1 = ei;        const int* dst1 = ei + EE;
  const int* src2 = dei;       const int* dst2 = dei + EE;

  const int eb = (EE+255)/256;

  // CSR for event graph (used by g1, g2, c1)
  hipMemsetAsync(CNT, 0, (size_t)NN*4, stream);
  count_kernel<<<eb,256,0,stream>>>(dst1, CNT, EE);
  scan_kernel<<<1,1024,0,stream>>>(CNT, PTR1, CUR, NN);
  fill_kernel<<<eb,256,0,stream>>>(dst1, CUR, SLOT1, EE);
  // CSR for duration graph
  hipMemsetAsync(CNT, 0, (size_t)NN*4, stream);
  count_kernel<<<eb,256,0,stream>>>(dst2, CNT, EE);
  scan_kernel<<<1,1024,0,stream>>>(CNT, PTR2, CUR, NN);
  fill_kernel<<<eb,256,0,stream>>>(dst2, CUR, SLOT2, EE);

  // input mask
  mask_kernel<<<(NN*128/4+255)/256,256,0,stream>>>(x, XM, NN*128/4);

  const int grows = (NN+63)/64;

  // ---- g1 ----
  gather_kernel<128><<<(NN*32+255)/256,256,0,stream>>>(XM,128, PTR1,SLOT1, src1, ea, AGG,128, NN);
  gemm_kernel<128,true><<<dim3(grows,1),256,0,stream>>>(AGG,128, g1_Wr, XM,128, g1_Wrt,128,
                                                        g1_br, nullptr, F1,128, NN);
  // ---- g2 ----
  gather_kernel<128><<<(NN*32+255)/256,256,0,stream>>>(F1,128, PTR1,SLOT1, src1, ea, AGG,128, NN);
  gemm_kernel<128,true><<<dim3(grows,1),256,0,stream>>>(AGG,128, g2_Wr, F1,128, g2_Wrt,128,
                                                        g2_br, nullptr, XC,256, NN);
  // ---- duration branch (into XC cols 128..255) ----
  gather_kernel<64><<<(NN*16+255)/256,256,0,stream>>>(dx,64, PTR2,SLOT2, src2, dea, AGG,64, NN);
  gemm_kernel<64,true><<<dim3(grows,1),256,0,stream>>>(AGG,64, d1_Wr, dx,64, d1_Wrt,128,
                                                       d1_br, nullptr, XC+128,256, NN);
  // ---- Wsum = c1_Wroot + skip_W (skip folded into root GEMM) ----
  addw_kernel<<<(256*256/4+255)/256,256,0,stream>>>(c1_Wrt, skip_W, WSUM, 256*256/4);
  // ---- c1 + skip ----
  gather_kernel<256><<<(NN*64+255)/256,256,0,stream>>>(XC,256, PTR1,SLOT1, src1, ea, AGG,256, NN);
  gemm_kernel<256,true><<<dim3(grows,2),256,0,stream>>>(AGG,256, c1_Wr, XC,256, WSUM,256,
                                                        c1_br, skip_b, XC2,256, NN);
  // ---- mean pool ----
  pool_kernel<<<BB,256,0,stream>>>(XC2, batch, EMB, NN);
  // ---- sequence MLP ----
  seq_kernel<<<BB,256,0,stream>>>(seq, fc1_W, fc1_b, fc2_W, fc2_b, S2B);
  // ---- head ----
  head_kernel<<<BB,256,0,stream>>>(EMB, S2B, fcc_W, fcc_b, cls_W, cls_b, out);
}

// Round 2
// 1034.034 us; speedup vs baseline: 1.7326x; 1.7326x over previous
//
#include <hip/hip_runtime.h>

#define NN 50000
#define MP 50176   // row-padded (multiple of 128)
#define EE 800000
#define BB 64

typedef __attribute__((ext_vector_type(8))) __bf16 bf16x8;
typedef __attribute__((ext_vector_type(4))) float f32x4;
typedef __attribute__((ext_vector_type(8))) unsigned short u16x8;

__device__ __forceinline__ float bu2f(unsigned short u){
  union { unsigned u32; float f; } c; c.u32 = ((unsigned)u) << 16; return c.f;
}
__device__ __forceinline__ unsigned short f2bu(float f){
  union { __bf16 h; unsigned short u; } c; c.h = (__bf16)f; return c.u;
}

// ---------------- split rows to hi/lo bf16 (optional -1 masking) ----------------
template<bool MASK>
__global__ __launch_bounds__(256)
void split_rows_kernel(const float* __restrict__ x, unsigned short* __restrict__ oh,
                       unsigned short* __restrict__ ol, int n8){
  int i = blockIdx.x*blockDim.x + threadIdx.x;
  if (i >= n8) return;
  float4 a = ((const float4*)x)[2*i];
  float4 b = ((const float4*)x)[2*i+1];
  float v[8] = {a.x,a.y,a.z,a.w,b.x,b.y,b.z,b.w};
  u16x8 h, l;
  #pragma unroll
  for (int j=0;j<8;j++){
    float f = v[j];
    if (MASK && f == -1.0f) f = 0.f;
    unsigned short hu = f2bu(f);
    h[j] = hu;
    l[j] = f2bu(f - bu2f(hu));
  }
  ((u16x8*)oh)[i] = h;
  ((u16x8*)ol)[i] = l;
}

// ---------------- transpose + split weights: W[K][N](+add) -> Wt[N][K] hi/lo ----------------
__global__ __launch_bounds__(256)
void tsplit_kernel(const float* __restrict__ W, const float* __restrict__ add,
                   int K, int N, unsigned short* __restrict__ oh, unsigned short* __restrict__ ol){
  int i = blockIdx.x*blockDim.x + threadIdx.x;
  if (i >= K*N) return;
  int k = i / N, n = i - k*N;
  float v = W[i] + (add ? add[i] : 0.f);
  unsigned short hu = f2bu(v);
  oh[(size_t)n*K + k] = hu;
  ol[(size_t)n*K + k] = f2bu(v - bu2f(hu));
}

// ---------------- CSR build ----------------
__global__ void count_kernel(const int* __restrict__ dst, int* __restrict__ cnt, int e){
  int i = blockIdx.x*blockDim.x + threadIdx.x;
  if (i < e) atomicAdd(&cnt[dst[i]], 1);
}

__global__ __launch_bounds__(1024)
void scan_kernel(const int* __restrict__ cnt, int* __restrict__ ptr, int* __restrict__ cur, int n){
  __shared__ int s[1024];
  int t = threadIdx.x;
  const int chunk = (n + 1023)/1024;
  int i0 = t*chunk;
  int i1 = i0 + chunk; if (i1 > n) i1 = n;
  int local = 0;
  for (int i=i0;i<i1;i++) local += cnt[i];
  s[t] = local; __syncthreads();
  for (int off=1; off<1024; off<<=1){
    int v = (t>=off) ? s[t-off] : 0;
    __syncthreads();
    s[t] += v;
    __syncthreads();
  }
  int run = s[t] - local;
  for (int i=i0;i<i1;i++){ ptr[i]=run; cur[i]=run; run += cnt[i]; }
  if (t==1023) ptr[n] = s[1023];
}

__global__ void fill_kernel(const int* __restrict__ dst, const int* __restrict__ src,
                            const float* __restrict__ ew, int* __restrict__ cur,
                            int* __restrict__ srcs, float* __restrict__ wts, int e){
  int i = blockIdx.x*blockDim.x + threadIdx.x;
  if (i < e){
    int p = atomicAdd(&cur[dst[i]], 1);
    srcs[p] = src[i];
    wts[p]  = ew[i];
  }
}

// ---------------- CSR gather on hi/lo bf16 rows ----------------
template<int F>
__global__ __launch_bounds__(256)
void gather_kernel(const unsigned short* __restrict__ Hh, const unsigned short* __restrict__ Hl,
                   int ldh,
                   const int* __restrict__ ptr, const int* __restrict__ srcs,
                   const float* __restrict__ wts,
                   unsigned short* __restrict__ Oh, unsigned short* __restrict__ Ol, int ldo){
  const int L = F/8;
  int gt = blockIdx.x*blockDim.x + threadIdx.x;
  int node = gt / L, lane = gt % L;
  if (node >= NN) return;
  int lo = ptr[node], hi = ptr[node+1];
  float acc[8] = {0,0,0,0,0,0,0,0};
  for (int p=lo;p<hi;++p){
    int s = srcs[p];
    float w = wts[p];
    u16x8 vh = *(const u16x8*)(Hh + (size_t)s*ldh + lane*8);
    u16x8 vl = *(const u16x8*)(Hl + (size_t)s*ldh + lane*8);
    #pragma unroll
    for (int j=0;j<8;j++) acc[j] += w*(bu2f(vh[j]) + bu2f(vl[j]));
  }
  u16x8 oh, ol;
  #pragma unroll
  for (int j=0;j<8;j++){
    unsigned short hu = f2bu(acc[j]);
    oh[j] = hu;
    ol[j] = f2bu(acc[j] - bu2f(hu));
  }
  *(u16x8*)(Oh + (size_t)node*ldo + lane*8) = oh;
  *(u16x8*)(Ol + (size_t)node*ldo + lane*8) = ol;
}

// ---------------- split-bf16 MFMA dual GEMM ----------------
// out = relu( A@W1 + R@W2 + b1 (+ b2) ); A,R,W given as hi/lo bf16; W pre-transposed [N][K].
// tile 128x128, BK=64, 4 waves (2x2 of 64x64), 16x16x32 MFMA, 3-term split product.
__device__ __forceinline__ int lds_off(int r, int slot){ return r*64 + ((slot ^ (r&7))<<3); }

template<bool SPLIT_OUT>
__global__ __launch_bounds__(256,2)
void mfma_gemm_kernel(const unsigned short* __restrict__ Ah, const unsigned short* __restrict__ Al, int K1,
                      const unsigned short* __restrict__ W1h, const unsigned short* __restrict__ W1l,
                      const unsigned short* __restrict__ Rh, const unsigned short* __restrict__ Rl, int K2,
                      const unsigned short* __restrict__ W2h, const unsigned short* __restrict__ W2l,
                      const float* __restrict__ b1, const float* __restrict__ b2,
                      float* __restrict__ outf, unsigned short* __restrict__ Oh,
                      unsigned short* __restrict__ Ol, int ldo, int coloff){
  __shared__ unsigned short sAh[128*64], sAl[128*64], sBh[128*64], sBl[128*64];
  const int tid  = threadIdx.x;
  const int lane = tid & 63;
  const int wave = tid >> 6;
  const int wr = (wave>>1)*64, wc = (wave&1)*64;
  const int row0 = blockIdx.x*128;
  const int col0 = blockIdx.y*128;

  f32x4 acc[4][4];
  #pragma unroll
  for (int a=0;a<4;a++)
    #pragma unroll
    for (int b=0;b<4;b++){ acc[a][b][0]=0.f; acc[a][b][1]=0.f; acc[a][b][2]=0.f; acc[a][b][3]=0.f; }

  #pragma unroll 1
  for (int pass=0; pass<2; ++pass){
    const unsigned short* Ahp = pass ? Rh  : Ah;
    const unsigned short* Alp = pass ? Rl  : Al;
    const unsigned short* Bhp = pass ? W2h : W1h;
    const unsigned short* Blp = pass ? W2l : W1l;
    const int K = pass ? K2 : K1;
    #pragma unroll 1
    for (int k0=0; k0<K; k0+=64){
      __syncthreads();
      #pragma unroll
      for (int i=0;i<4;i++){
        int c = tid + i*256;
        int r = c >> 3, s = c & 7;
        int lo = lds_off(r, s);
        size_t ga = (size_t)(row0+r)*K + k0 + s*8;
        size_t gb = (size_t)(col0+r)*K + k0 + s*8;
        *(u16x8*)&sAh[lo] = *(const u16x8*)(Ahp + ga);
        *(u16x8*)&sAl[lo] = *(const u16x8*)(Alp + ga);
        *(u16x8*)&sBh[lo] = *(const u16x8*)(Bhp + gb);
        *(u16x8*)&sBl[lo] = *(const u16x8*)(Blp + gb);
      }
      __syncthreads();
      #pragma unroll
      for (int ks=0; ks<2; ++ks){
        const int rsel = lane >> 4;        // 0..3
        bf16x8 ahf[4], alf[4];
        #pragma unroll
        for (int mf=0; mf<4; mf++){
          int r = wr + mf*16 + (lane&15);
          int off = lds_off(r, ks*4 + rsel);
          ahf[mf] = *(const bf16x8*)&sAh[off];
          alf[mf] = *(const bf16x8*)&sAl[off];
        }
        #pragma unroll
        for (int nf=0; nf<4; nf++){
          int cix = wc + nf*16 + (lane&15);
          int off = lds_off(cix, ks*4 + rsel);
          bf16x8 bh = *(const bf16x8*)&sBh[off];
          bf16x8 bl = *(const bf16x8*)&sBl[off];
          #pragma unroll
          for (int mf=0; mf<4; mf++){
            acc[mf][nf] = __builtin_amdgcn_mfma_f32_16x16x32_bf16(ahf[mf], bh, acc[mf][nf], 0,0,0);
            acc[mf][nf] = __builtin_amdgcn_mfma_f32_16x16x32_bf16(alf[mf], bh, acc[mf][nf], 0,0,0);
            acc[mf][nf] = __builtin_amdgcn_mfma_f32_16x16x32_bf16(ahf[mf], bl, acc[mf][nf], 0,0,0);
          }
        }
      }
    }
  }

  // epilogue: C[row][col], row=(lane>>4)*4+reg, col=lane&15
  #pragma unroll
  for (int nf=0; nf<4; nf++){
    int colg = col0 + wc + nf*16 + (lane&15);
    float bias = b1[colg] + (b2 ? b2[colg] : 0.f);
    #pragma unroll
    for (int mf=0; mf<4; mf++){
      #pragma unroll
      for (int r=0; r<4; r++){
        int rowg = row0 + wr + mf*16 + (lane>>4)*4 + r;
        if (rowg < NN){
          float o = fmaxf(acc[mf][nf][r] + bias, 0.f);
          if (SPLIT_OUT){
            unsigned short hu = f2bu(o);
            Oh[(size_t)rowg*ldo + coloff + colg] = hu;
            Ol[(size_t)rowg*ldo + coloff + colg] = f2bu(o - bu2f(hu));
          } else {
            outf[(size_t)rowg*ldo + coloff + colg] = o;
          }
        }
      }
    }
  }
}

// ---------------- mean pool per batch (batch sorted) ----------------
__device__ __forceinline__ int lower_bound_i(const int* __restrict__ arr, int n, int v){
  int lo=0, hi=n;
  while (lo < hi){ int mid=(lo+hi)>>1; if (arr[mid] < v) lo=mid+1; else hi=mid; }
  return lo;
}

__global__ __launch_bounds__(256)
void pool_kernel(const float* __restrict__ xc2, const int* __restrict__ batch,
                 float* __restrict__ emb, int n){
  int b = blockIdx.x;
  int lo = lower_bound_i(batch, n, b);
  int hi = lower_bound_i(batch, n, b+1);
  float s = 0.f;
  for (int r=lo; r<hi; ++r) s += xc2[(size_t)r*256 + threadIdx.x];
  float c = (float)(hi - lo);
  emb[b*256 + threadIdx.x] = s / fmaxf(c, 1.0f);
}

// ---------------- sequence MLP ----------------
__global__ __launch_bounds__(256)
void seq_kernel(const float* __restrict__ seq,
                const float* __restrict__ W1, const float* __restrict__ b1,
                const float* __restrict__ W2, const float* __restrict__ b2,
                float* __restrict__ s2){
  __shared__ float sin_[256], s1[256];
  int b = blockIdx.x, t = threadIdx.x;
  sin_[t] = seq[b*256 + t];
  __syncthreads();
  float a = b1[t];
  for (int k=0;k<256;k++) a += sin_[k]*W1[k*256 + t];
  s1[t] = fmaxf(a, 0.f);
  __syncthreads();
  if (t < 128){
    float a2 = b2[t];
    for (int k=0;k<256;k++) a2 += s1[k]*W2[k*128 + t];
    s2[b*128 + t] = fmaxf(a2, 0.f);
  }
}

// ---------------- fused head ----------------
__global__ __launch_bounds__(256)
void head_kernel(const float* __restrict__ emb, const float* __restrict__ s2,
                 const float* __restrict__ fccW, const float* __restrict__ fccb,
                 const float* __restrict__ clsW, const float* __restrict__ clsb,
                 float* __restrict__ out){
  __shared__ float h[384], h2[256], lg[16];
  __shared__ float mred, lred;
  int b = blockIdx.x, t = threadIdx.x;
  h[t] = emb[b*256 + t];
  if (t < 128) h[256 + t] = s2[b*128 + t];
  __syncthreads();
  float a = fccb[t];
  for (int k=0;k<384;k++) a += h[k]*fccW[k*256 + t];
  h2[t] = fmaxf(a, 0.f);
  __syncthreads();
  if (t < 16){
    float a2 = clsb[t];
    for (int k=0;k<256;k++) a2 += h2[k]*clsW[k*16 + t];
    lg[t] = a2;
  }
  __syncthreads();
  if (t == 0){
    float m = lg[0];
    for (int i=1;i<16;i++) m = fmaxf(m, lg[i]);
    float s = 0.f;
    for (int i=0;i<16;i++) s += expf(lg[i]-m);
    mred = m; lred = logf(s);
  }
  __syncthreads();
  if (t < 16) out[b*16 + t] = lg[t] - mred - lred;
}

extern "C" void kernel_launch(void* const* d_in, const int* in_sizes, int n_in,
                              void* d_out, int out_size, void* d_ws, size_t ws_size,
                              hipStream_t stream){
  const float* x      = (const float*)d_in[0];
  const int*   ei     = (const int*)  d_in[1];
  const float* ea     = (const float*)d_in[2];
  const int*   batch  = (const int*)  d_in[3];
  const float* dx     = (const float*)d_in[4];
  const int*   dei    = (const int*)  d_in[5];
  const float* dea    = (const float*)d_in[6];
  const float* seq    = (const float*)d_in[7];
  const float* g1_Wr  = (const float*)d_in[8];
  const float* g1_br  = (const float*)d_in[9];
  const float* g1_Wrt = (const float*)d_in[10];
  const float* g2_Wr  = (const float*)d_in[11];
  const float* g2_br  = (const float*)d_in[12];
  const float* g2_Wrt = (const float*)d_in[13];
  const float* d1_Wr  = (const float*)d_in[14];
  const float* d1_br  = (const float*)d_in[15];
  const float* d1_Wrt = (const float*)d_in[16];
  const float* c1_Wr  = (const float*)d_in[17];
  const float* c1_br  = (const float*)d_in[18];
  const float* c1_Wrt = (const float*)d_in[19];
  const float* skip_W = (const float*)d_in[20];
  const float* skip_b = (const float*)d_in[21];
  const float* fc1_W  = (const float*)d_in[22];
  const float* fc1_b  = (const float*)d_in[23];
  const float* fc2_W  = (const float*)d_in[24];
  const float* fc2_b  = (const float*)d_in[25];
  const float* fcc_W  = (const float*)d_in[26];
  const float* fcc_b  = (const float*)d_in[27];
  const float* cls_W  = (const float*)d_in[28];
  const float* cls_b  = (const float*)d_in[29];
  float* out = (float*)d_out;

  char* wp = (char*)d_ws;
  auto alloc = [&](size_t bytes)->char*{
    char* p = wp; wp += (bytes + 255) & ~(size_t)255; return p;
  };
  // XM + F1 region (later aliased by XC2 fp32)
  unsigned short* XMh = (unsigned short*)alloc((size_t)MP*128*2);
  unsigned short* XMl = (unsigned short*)alloc((size_t)MP*128*2);
  unsigned short* F1h = (unsigned short*)alloc((size_t)MP*128*2);
  unsigned short* F1l = (unsigned short*)alloc((size_t)MP*128*2);
  float* XC2 = (float*)XMh;   // alias: 4*MP*128*2 == MP*256*4
  unsigned short* DXh = (unsigned short*)alloc((size_t)MP*64*2);
  unsigned short* DXl = (unsigned short*)alloc((size_t)MP*64*2);
  unsigned short* XCh = (unsigned short*)alloc((size_t)MP*256*2);
  unsigned short* XCl = (unsigned short*)alloc((size_t)MP*256*2);
  unsigned short* AGh = (unsigned short*)alloc((size_t)MP*256*2);
  unsigned short* AGl = (unsigned short*)alloc((size_t)MP*256*2);
  // transposed split weights
  unsigned short* T1h = (unsigned short*)alloc(128*128*2); unsigned short* T1l = (unsigned short*)alloc(128*128*2);
  unsigned short* T2h = (unsigned short*)alloc(128*128*2); unsigned short* T2l = (unsigned short*)alloc(128*128*2);
  unsigned short* T3h = (unsigned short*)alloc(128*128*2); unsigned short* T3l = (unsigned short*)alloc(128*128*2);
  unsigned short* T4h = (unsigned short*)alloc(128*128*2); unsigned short* T4l = (unsigned short*)alloc(128*128*2);
  unsigned short* T5h = (unsigned short*)alloc(64*128*2);  unsigned short* T5l = (unsigned short*)alloc(64*128*2);
  unsigned short* T6h = (unsigned short*)alloc(64*128*2);  unsigned short* T6l = (unsigned short*)alloc(64*128*2);
  unsigned short* T7h = (unsigned short*)alloc(256*256*2); unsigned short* T7l = (unsigned short*)alloc(256*256*2);
  unsigned short* T8h = (unsigned short*)alloc(256*256*2); unsigned short* T8l = (unsigned short*)alloc(256*256*2);
  // CSR
  int*   PTR1 = (int*)alloc((size_t)(NN+1)*4);
  int*   SRC1 = (int*)alloc((size_t)EE*4);
  float* WT1  = (float*)alloc((size_t)EE*4);
  int*   PTR2 = (int*)alloc((size_t)(NN+1)*4);
  int*   SRC2 = (int*)alloc((size_t)EE*4);
  float* WT2  = (float*)alloc((size_t)EE*4);
  int*   CNT  = (int*)alloc((size_t)NN*4);
  int*   CUR  = (int*)alloc((size_t)NN*4);
  float* EMB  = (float*)alloc((size_t)BB*256*4);
  float* S2B  = (float*)alloc((size_t)BB*128*4);

  const int* src1 = ei;  const int* dst1 = ei + EE;
  const int* src2 = dei; const int* dst2 = dei + EE;
  const int eb = (EE+255)/256;

  // CSR event graph
  hipMemsetAsync(CNT, 0, (size_t)NN*4, stream);
  count_kernel<<<eb,256,0,stream>>>(dst1, CNT, EE);
  scan_kernel<<<1,1024,0,stream>>>(CNT, PTR1, CUR, NN);
  fill_kernel<<<eb,256,0,stream>>>(dst1, src1, ea, CUR, SRC1, WT1, EE);
  // CSR duration graph
  hipMemsetAsync(CNT, 0, (size_t)NN*4, stream);
  count_kernel<<<eb,256,0,stream>>>(dst2, CNT, EE);
  scan_kernel<<<1,1024,0,stream>>>(CNT, PTR2, CUR, NN);
  fill_kernel<<<eb,256,0,stream>>>(dst2, src2, dea, CUR, SRC2, WT2, EE);

  // splits
  split_rows_kernel<true ><<<(NN*16+255)/256,256,0,stream>>>(x,  XMh, XMl, NN*16);
  split_rows_kernel<false><<<(NN*8 +255)/256,256,0,stream>>>(dx, DXh, DXl, NN*8);

  // weight prep (transpose + split; T8 = c1_Wroot + skip_W)
  tsplit_kernel<<<(128*128+255)/256,256,0,stream>>>(g1_Wr,  nullptr, 128,128, T1h,T1l);
  tsplit_kernel<<<(128*128+255)/256,256,0,stream>>>(g1_Wrt, nullptr, 128,128, T2h,T2l);
  tsplit_kernel<<<(128*128+255)/256,256,0,stream>>>(g2_Wr,  nullptr, 128,128, T3h,T3l);
  tsplit_kernel<<<(128*128+255)/256,256,0,stream>>>(g2_Wrt, nullptr, 128,128, T4h,T4l);
  tsplit_kernel<<<(64*128 +255)/256,256,0,stream>>>(d1_Wr,  nullptr, 64,128,  T5h,T5l);
  tsplit_kernel<<<(64*128 +255)/256,256,0,stream>>>(d1_Wrt, nullptr, 64,128,  T6h,T6l);
  tsplit_kernel<<<(256*256+255)/256,256,0,stream>>>(c1_Wr,  nullptr, 256,256, T7h,T7l);
  tsplit_kernel<<<(256*256+255)/256,256,0,stream>>>(c1_Wrt, skip_W,  256,256, T8h,T8l);

  const int GB = (NN+127)/128;   // 391

  // ---- g1 ----
  gather_kernel<128><<<(NN*16+255)/256,256,0,stream>>>(XMh,XMl,128, PTR1,SRC1,WT1, AGh,AGl,128);
  mfma_gemm_kernel<true><<<dim3(GB,1),256,0,stream>>>(AGh,AGl,128, T1h,T1l, XMh,XMl,128, T2h,T2l,
                                                      g1_br, nullptr, nullptr, F1h,F1l, 128, 0);
  // ---- g2 ----
  gather_kernel<128><<<(NN*16+255)/256,256,0,stream>>>(F1h,F1l,128, PTR1,SRC1,WT1, AGh,AGl,128);
  mfma_gemm_kernel<true><<<dim3(GB,1),256,0,stream>>>(AGh,AGl,128, T3h,T3l, F1h,F1l,128, T4h,T4l,
                                                      g2_br, nullptr, nullptr, XCh,XCl, 256, 0);
  // ---- duration branch -> XC cols 128..255 ----
  gather_kernel<64><<<(NN*8+255)/256,256,0,stream>>>(DXh,DXl,64, PTR2,SRC2,WT2, AGh,AGl,64);
  mfma_gemm_kernel<true><<<dim3(GB,1),256,0,stream>>>(AGh,AGl,64, T5h,T5l, DXh,DXl,64, T6h,T6l,
                                                      d1_br, nullptr, nullptr, XCh,XCl, 256, 128);
  // ---- c1 + folded skip ----
  gather_kernel<256><<<(NN*32+255)/256,256,0,stream>>>(XCh,XCl,256, PTR1,SRC1,WT1, AGh,AGl,256);
  mfma_gemm_kernel<false><<<dim3(GB,2),256,0,stream>>>(AGh,AGl,256, T7h,T7l, XCh,XCl,256, T8h,T8l,
                                                       c1_br, skip_b, XC2, nullptr,nullptr, 256, 0);
  // ---- pool / seq / head ----
  pool_kernel<<<BB,256,0,stream>>>(XC2, batch, EMB, NN);
  seq_kernel<<<BB,256,0,stream>>>(seq, fc1_W, fc1_b, fc2_W, fc2_b, S2B);
  head_kernel<<<BB,256,0,stream>>>(EMB, S2B, fcc_W, fcc_b, cls_W, cls_b, out);
}

// Round 3
// 767.417 us; speedup vs baseline: 2.3346x; 1.3474x over previous
//
#include <hip/hip_runtime.h>

#define NN 50000
#define MP 50176   // row-padded (multiple of 128)
#define EE 800000
#define BB 64

typedef _Float16 half_t;
typedef __attribute__((ext_vector_type(8))) _Float16 h16x8;
typedef __attribute__((ext_vector_type(8))) __bf16 bf16x8;
typedef __attribute__((ext_vector_type(4))) float f32x4;
typedef __attribute__((ext_vector_type(8))) unsigned short u16x8;

__device__ __forceinline__ float bu2f(unsigned short u){
  union { unsigned u32; float f; } c; c.u32 = ((unsigned)u) << 16; return c.f;
}
__device__ __forceinline__ unsigned short f2bu(float f){
  union { __bf16 h; unsigned short u; } c; c.h = (__bf16)f; return c.u;
}

// ---------------- fp32 rows -> fp16 rows (optional -1 masking) ----------------
template<bool MASK>
__global__ __launch_bounds__(256)
void tohalf_kernel(const float* __restrict__ x, half_t* __restrict__ o, int n8){
  int i = blockIdx.x*blockDim.x + threadIdx.x;
  if (i >= n8) return;
  float4 a = ((const float4*)x)[2*i];
  float4 b = ((const float4*)x)[2*i+1];
  float v[8] = {a.x,a.y,a.z,a.w,b.x,b.y,b.z,b.w};
  h16x8 h;
  #pragma unroll
  for (int j=0;j<8;j++){
    float f = v[j];
    if (MASK && f == -1.0f) f = 0.f;
    h[j] = (half_t)f;
  }
  ((h16x8*)o)[i] = h;
}

// ---------------- transpose + split weights: W[K][N](+add) -> Wt[N][K] hi/lo ----------------
__global__ __launch_bounds__(256)
void tsplit_kernel(const float* __restrict__ W, const float* __restrict__ add,
                   int K, int N, unsigned short* __restrict__ oh, unsigned short* __restrict__ ol){
  int i = blockIdx.x*blockDim.x + threadIdx.x;
  if (i >= K*N) return;
  int k = i / N, n = i - k*N;
  float v = W[i] + (add ? add[i] : 0.f);
  unsigned short hu = f2bu(v);
  oh[(size_t)n*K + k] = hu;
  ol[(size_t)n*K + k] = f2bu(v - bu2f(hu));
}

// ---------------- CSR build ----------------
__global__ void count_kernel(const int* __restrict__ dst, int* __restrict__ cnt, int e){
  int i = blockIdx.x*blockDim.x + threadIdx.x;
  if (i < e) atomicAdd(&cnt[dst[i]], 1);
}

__global__ __launch_bounds__(1024)
void scan_kernel(const int* __restrict__ cnt, int* __restrict__ ptr, int* __restrict__ cur, int n){
  __shared__ int s[1024];
  int t = threadIdx.x;
  const int chunk = (n + 1023)/1024;
  int i0 = t*chunk;
  int i1 = i0 + chunk; if (i1 > n) i1 = n;
  int local = 0;
  for (int i=i0;i<i1;i++) local += cnt[i];
  s[t] = local; __syncthreads();
  for (int off=1; off<1024; off<<=1){
    int v = (t>=off) ? s[t-off] : 0;
    __syncthreads();
    s[t] += v;
    __syncthreads();
  }
  int run = s[t] - local;
  for (int i=i0;i<i1;i++){ ptr[i]=run; cur[i]=run; run += cnt[i]; }
  if (t==1023) ptr[n] = s[1023];
}

__global__ void fill_kernel(const int* __restrict__ dst, const int* __restrict__ src,
                            const float* __restrict__ ew, int* __restrict__ cur,
                            int2* __restrict__ esw, int e){
  int i = blockIdx.x*blockDim.x + threadIdx.x;
  if (i < e){
    int p = atomicAdd(&cur[dst[i]], 1);
    esw[p] = make_int2(src[i], __float_as_int(ew[i]));
  }
}

// ---------------- CSR gather on fp16 rows, split-bf16 output ----------------
template<int F>
__global__ __launch_bounds__(256)
void gather_kernel(const half_t* __restrict__ H, int ldh,
                   const int* __restrict__ ptr, const int2* __restrict__ esw,
                   unsigned short* __restrict__ Oh, unsigned short* __restrict__ Ol, int ldo){
  const int L = F/8;
  int gt = blockIdx.x*blockDim.x + threadIdx.x;
  int node = gt / L, lane = gt - node*L;
  if (node >= NN) return;
  int lo = ptr[node], hi = ptr[node+1];
  float acc[8] = {0,0,0,0,0,0,0,0};
  int p = lo;
  #pragma unroll 1
  for (; p+4 <= hi; p += 4){
    int2 e0 = esw[p], e1 = esw[p+1], e2 = esw[p+2], e3 = esw[p+3];
    h16x8 v0 = *(const h16x8*)(H + (size_t)e0.x*ldh + lane*8);
    h16x8 v1 = *(const h16x8*)(H + (size_t)e1.x*ldh + lane*8);
    h16x8 v2 = *(const h16x8*)(H + (size_t)e2.x*ldh + lane*8);
    h16x8 v3 = *(const h16x8*)(H + (size_t)e3.x*ldh + lane*8);
    float w0 = __int_as_float(e0.y), w1 = __int_as_float(e1.y);
    float w2 = __int_as_float(e2.y), w3 = __int_as_float(e3.y);
    #pragma unroll
    for (int j=0;j<8;j++)
      acc[j] += w0*(float)v0[j] + w1*(float)v1[j] + w2*(float)v2[j] + w3*(float)v3[j];
  }
  for (; p < hi; ++p){
    int2 e = esw[p];
    h16x8 v = *(const h16x8*)(H + (size_t)e.x*ldh + lane*8);
    float w = __int_as_float(e.y);
    #pragma unroll
    for (int j=0;j<8;j++) acc[j] += w*(float)v[j];
  }
  u16x8 oh, ol;
  #pragma unroll
  for (int j=0;j<8;j++){
    unsigned short hu = f2bu(acc[j]);
    oh[j] = hu;
    ol[j] = f2bu(acc[j] - bu2f(hu));
  }
  *(u16x8*)(Oh + (size_t)node*ldo + lane*8) = oh;
  *(u16x8*)(Ol + (size_t)node*ldo + lane*8) = ol;
}

// ---------------- split-bf16 MFMA dual GEMM ----------------
// out = relu( A@W1 + R@W2 + b1 (+ b2) ); A pre-split hi/lo bf16; R fp16 (split at stage);
// W pre-transposed [N][K] hi/lo. tile 128x128, BK=64, 4 waves, 16x16x32 MFMA.
__device__ __forceinline__ int lds_off(int r, int slot){ return r*64 + ((slot ^ (r&7))<<3); }

template<bool OUT16>
__global__ __launch_bounds__(256,2)
void mfma_gemm_kernel(const unsigned short* __restrict__ Ah, const unsigned short* __restrict__ Al, int K1,
                      const unsigned short* __restrict__ W1h, const unsigned short* __restrict__ W1l,
                      const half_t* __restrict__ Rf, int K2,
                      const unsigned short* __restrict__ W2h, const unsigned short* __restrict__ W2l,
                      const float* __restrict__ b1, const float* __restrict__ b2,
                      float* __restrict__ outf, half_t* __restrict__ out16, int ldo, int coloff){
  __shared__ unsigned short sAh[128*64], sAl[128*64], sBh[128*64], sBl[128*64];
  const int tid  = threadIdx.x;
  const int lane = tid & 63;
  const int wave = tid >> 6;
  const int wr = (wave>>1)*64, wc = (wave&1)*64;
  const int row0 = blockIdx.x*128;
  const int col0 = blockIdx.y*128;

  f32x4 acc[4][4];
  #pragma unroll
  for (int a=0;a<4;a++)
    #pragma unroll
    for (int b=0;b<4;b++){ acc[a][b][0]=0.f; acc[a][b][1]=0.f; acc[a][b][2]=0.f; acc[a][b][3]=0.f; }

  #pragma unroll 1
  for (int pass=0; pass<2; ++pass){
    const unsigned short* Bhp = pass ? W2h : W1h;
    const unsigned short* Blp = pass ? W2l : W1l;
    const int K = pass ? K2 : K1;
    #pragma unroll 1
    for (int k0=0; k0<K; k0+=64){
      __syncthreads();
      #pragma unroll
      for (int i=0;i<4;i++){
        int c = tid + i*256;
        int r = c >> 3, s = c & 7;
        int lo = lds_off(r, s);
        size_t gb = (size_t)(col0+r)*K + k0 + s*8;
        *(u16x8*)&sBh[lo] = *(const u16x8*)(Bhp + gb);
        *(u16x8*)&sBl[lo] = *(const u16x8*)(Blp + gb);
        if (pass == 0){
          size_t ga = (size_t)(row0+r)*K1 + k0 + s*8;
          *(u16x8*)&sAh[lo] = *(const u16x8*)(Ah + ga);
          *(u16x8*)&sAl[lo] = *(const u16x8*)(Al + ga);
        } else {
          h16x8 v = *(const h16x8*)(Rf + (size_t)(row0+r)*K2 + k0 + s*8);
          u16x8 hh, ll;
          #pragma unroll
          for (int j=0;j<8;j++){
            float f = (float)v[j];
            unsigned short hu = f2bu(f);
            hh[j] = hu;
            ll[j] = f2bu(f - bu2f(hu));
          }
          *(u16x8*)&sAh[lo] = hh;
          *(u16x8*)&sAl[lo] = ll;
        }
      }
      __syncthreads();
      #pragma unroll
      for (int ks=0; ks<2; ++ks){
        const int rsel = lane >> 4;
        bf16x8 ahf[4], alf[4];
        #pragma unroll
        for (int mf=0; mf<4; mf++){
          int r = wr + mf*16 + (lane&15);
          int off = lds_off(r, ks*4 + rsel);
          ahf[mf] = *(const bf16x8*)&sAh[off];
          alf[mf] = *(const bf16x8*)&sAl[off];
        }
        #pragma unroll
        for (int nf=0; nf<4; nf++){
          int cix = wc + nf*16 + (lane&15);
          int off = lds_off(cix, ks*4 + rsel);
          bf16x8 bh = *(const bf16x8*)&sBh[off];
          bf16x8 bl = *(const bf16x8*)&sBl[off];
          #pragma unroll
          for (int mf=0; mf<4; mf++){
            acc[mf][nf] = __builtin_amdgcn_mfma_f32_16x16x32_bf16(ahf[mf], bh, acc[mf][nf], 0,0,0);
            acc[mf][nf] = __builtin_amdgcn_mfma_f32_16x16x32_bf16(alf[mf], bh, acc[mf][nf], 0,0,0);
            acc[mf][nf] = __builtin_amdgcn_mfma_f32_16x16x32_bf16(ahf[mf], bl, acc[mf][nf], 0,0,0);
          }
        }
      }
    }
  }

  // epilogue: C[row][col], row=(lane>>4)*4+reg, col=lane&15
  #pragma unroll
  for (int nf=0; nf<4; nf++){
    int colg = col0 + wc + nf*16 + (lane&15);
    float bias = b1[colg] + (b2 ? b2[colg] : 0.f);
    #pragma unroll
    for (int mf=0; mf<4; mf++){
      #pragma unroll
      for (int r=0; r<4; r++){
        int rowg = row0 + wr + mf*16 + (lane>>4)*4 + r;
        if (rowg < NN){
          float o = fmaxf(acc[mf][nf][r] + bias, 0.f);
          if (OUT16) out16[(size_t)rowg*ldo + coloff + colg] = (half_t)o;
          else       outf [(size_t)rowg*ldo + coloff + colg] = o;
        }
      }
    }
  }
}

// ---------------- two-phase mean pool (batch sorted) ----------------
__global__ __launch_bounds__(256)
void pool_partial_kernel(const float* __restrict__ xc2, const int* __restrict__ batch,
                         float* __restrict__ sums){
  int r0 = blockIdx.x*128;
  int r1 = r0 + 128; if (r1 > NN) r1 = NN;
  int t = threadIdx.x;
  float run = 0.f;
  int cb = batch[r0];
  for (int r=r0; r<r1; ++r){
    int b = batch[r];
    if (b != cb){ atomicAdd(&sums[cb*256 + t], run); run = 0.f; cb = b; }
    run += xc2[(size_t)r*256 + t];
  }
  atomicAdd(&sums[cb*256 + t], run);
}

__device__ __forceinline__ int lower_bound_i(const int* __restrict__ arr, int n, int v){
  int lo=0, hi=n;
  while (lo < hi){ int mid=(lo+hi)>>1; if (arr[mid] < v) lo=mid+1; else hi=mid; }
  return lo;
}

__global__ __launch_bounds__(256)
void pool_final_kernel(const float* __restrict__ sums, const int* __restrict__ batch,
                       float* __restrict__ emb){
  int b = blockIdx.x, t = threadIdx.x;
  int lo = lower_bound_i(batch, NN, b);
  int hi = lower_bound_i(batch, NN, b+1);
  emb[b*256 + t] = sums[b*256 + t] / fmaxf((float)(hi-lo), 1.0f);
}

// ---------------- sequence MLP ----------------
__global__ __launch_bounds__(256)
void seq_kernel(const float* __restrict__ seq,
                const float* __restrict__ W1, const float* __restrict__ b1,
                const float* __restrict__ W2, const float* __restrict__ b2,
                float* __restrict__ s2){
  __shared__ float sin_[256], s1[256];
  int b = blockIdx.x, t = threadIdx.x;
  sin_[t] = seq[b*256 + t];
  __syncthreads();
  float a = b1[t];
  for (int k=0;k<256;k++) a += sin_[k]*W1[k*256 + t];
  s1[t] = fmaxf(a, 0.f);
  __syncthreads();
  if (t < 128){
    float a2 = b2[t];
    for (int k=0;k<256;k++) a2 += s1[k]*W2[k*128 + t];
    s2[b*128 + t] = fmaxf(a2, 0.f);
  }
}

// ---------------- fused head ----------------
__global__ __launch_bounds__(256)
void head_kernel(const float* __restrict__ emb, const float* __restrict__ s2,
                 const float* __restrict__ fccW, const float* __restrict__ fccb,
                 const float* __restrict__ clsW, const float* __restrict__ clsb,
                 float* __restrict__ out){
  __shared__ float h[384], h2[256], lg[16];
  __shared__ float mred, lred;
  int b = blockIdx.x, t = threadIdx.x;
  h[t] = emb[b*256 + t];
  if (t < 128) h[256 + t] = s2[b*128 + t];
  __syncthreads();
  float a = fccb[t];
  for (int k=0;k<384;k++) a += h[k]*fccW[k*256 + t];
  h2[t] = fmaxf(a, 0.f);
  __syncthreads();
  if (t < 16){
    float a2 = clsb[t];
    for (int k=0;k<256;k++) a2 += h2[k]*clsW[k*16 + t];
    lg[t] = a2;
  }
  __syncthreads();
  if (t == 0){
    float m = lg[0];
    for (int i=1;i<16;i++) m = fmaxf(m, lg[i]);
    float s = 0.f;
    for (int i=0;i<16;i++) s += expf(lg[i]-m);
    mred = m; lred = logf(s);
  }
  __syncthreads();
  if (t < 16) out[b*16 + t] = lg[t] - mred - lred;
}

extern "C" void kernel_launch(void* const* d_in, const int* in_sizes, int n_in,
                              void* d_out, int out_size, void* d_ws, size_t ws_size,
                              hipStream_t stream){
  const float* x      = (const float*)d_in[0];
  const int*   ei     = (const int*)  d_in[1];
  const float* ea     = (const float*)d_in[2];
  const int*   batch  = (const int*)  d_in[3];
  const float* dx     = (const float*)d_in[4];
  const int*   dei    = (const int*)  d_in[5];
  const float* dea    = (const float*)d_in[6];
  const float* seq    = (const float*)d_in[7];
  const float* g1_Wr  = (const float*)d_in[8];
  const float* g1_br  = (const float*)d_in[9];
  const float* g1_Wrt = (const float*)d_in[10];
  const float* g2_Wr  = (const float*)d_in[11];
  const float* g2_br  = (const float*)d_in[12];
  const float* g2_Wrt = (const float*)d_in[13];
  const float* d1_Wr  = (const float*)d_in[14];
  const float* d1_br  = (const float*)d_in[15];
  const float* d1_Wrt = (const float*)d_in[16];
  const float* c1_Wr  = (const float*)d_in[17];
  const float* c1_br  = (const float*)d_in[18];
  const float* c1_Wrt = (const float*)d_in[19];
  const float* skip_W = (const float*)d_in[20];
  const float* skip_b = (const float*)d_in[21];
  const float* fc1_W  = (const float*)d_in[22];
  const float* fc1_b  = (const float*)d_in[23];
  const float* fc2_W  = (const float*)d_in[24];
  const float* fc2_b  = (const float*)d_in[25];
  const float* fcc_W  = (const float*)d_in[26];
  const float* fcc_b  = (const float*)d_in[27];
  const float* cls_W  = (const float*)d_in[28];
  const float* cls_b  = (const float*)d_in[29];
  float* out = (float*)d_out;

  char* wp = (char*)d_ws;
  auto alloc = [&](size_t bytes)->char*{
    char* p = wp; wp += (bytes + 255) & ~(size_t)255; return p;
  };
  half_t* XM16 = (half_t*)alloc((size_t)MP*128*2);
  half_t* F116 = (half_t*)alloc((size_t)MP*128*2);
  half_t* DX16 = (half_t*)alloc((size_t)MP*64*2);
  half_t* XC16 = (half_t*)alloc((size_t)MP*256*2);
  unsigned short* AGh = (unsigned short*)alloc((size_t)MP*256*2);
  unsigned short* AGl = (unsigned short*)alloc((size_t)MP*256*2);
  float* XC2 = (float*)alloc((size_t)MP*256*4);
  // transposed split weights
  unsigned short* T1h = (unsigned short*)alloc(128*128*2); unsigned short* T1l = (unsigned short*)alloc(128*128*2);
  unsigned short* T2h = (unsigned short*)alloc(128*128*2); unsigned short* T2l = (unsigned short*)alloc(128*128*2);
  unsigned short* T3h = (unsigned short*)alloc(128*128*2); unsigned short* T3l = (unsigned short*)alloc(128*128*2);
  unsigned short* T4h = (unsigned short*)alloc(128*128*2); unsigned short* T4l = (unsigned short*)alloc(128*128*2);
  unsigned short* T5h = (unsigned short*)alloc(64*128*2);  unsigned short* T5l = (unsigned short*)alloc(64*128*2);
  unsigned short* T6h = (unsigned short*)alloc(64*128*2);  unsigned short* T6l = (unsigned short*)alloc(64*128*2);
  unsigned short* T7h = (unsigned short*)alloc(256*256*2); unsigned short* T7l = (unsigned short*)alloc(256*256*2);
  unsigned short* T8h = (unsigned short*)alloc(256*256*2); unsigned short* T8l = (unsigned short*)alloc(256*256*2);
  // CSR
  int*  PTR1 = (int*)alloc((size_t)(NN+1)*4);
  int2* ESW1 = (int2*)alloc((size_t)EE*8);
  int*  PTR2 = (int*)alloc((size_t)(NN+1)*4);
  int2* ESW2 = (int2*)alloc((size_t)EE*8);
  int*  CNT  = (int*)alloc((size_t)NN*4);
  int*  CUR  = (int*)alloc((size_t)NN*4);
  float* EMBS = (float*)alloc((size_t)BB*256*4);
  float* EMB  = (float*)alloc((size_t)BB*256*4);
  float* S2B  = (float*)alloc((size_t)BB*128*4);

  const int* src1 = ei;  const int* dst1 = ei + EE;
  const int* src2 = dei; const int* dst2 = dei + EE;
  const int eb = (EE+255)/256;

  // CSR event graph
  hipMemsetAsync(CNT, 0, (size_t)NN*4, stream);
  count_kernel<<<eb,256,0,stream>>>(dst1, CNT, EE);
  scan_kernel<<<1,1024,0,stream>>>(CNT, PTR1, CUR, NN);
  fill_kernel<<<eb,256,0,stream>>>(dst1, src1, ea, CUR, ESW1, EE);
  // CSR duration graph
  hipMemsetAsync(CNT, 0, (size_t)NN*4, stream);
  count_kernel<<<eb,256,0,stream>>>(dst2, CNT, EE);
  scan_kernel<<<1,1024,0,stream>>>(CNT, PTR2, CUR, NN);
  fill_kernel<<<eb,256,0,stream>>>(dst2, src2, dea, CUR, ESW2, EE);

  // fp16 activations
  tohalf_kernel<true ><<<(NN*16+255)/256,256,0,stream>>>(x,  XM16, NN*16);
  tohalf_kernel<false><<<(NN*8 +255)/256,256,0,stream>>>(dx, DX16, NN*8);

  // weight prep (transpose + split; T8 = c1_Wroot + skip_W)
  tsplit_kernel<<<(128*128+255)/256,256,0,stream>>>(g1_Wr,  nullptr, 128,128, T1h,T1l);
  tsplit_kernel<<<(128*128+255)/256,256,0,stream>>>(g1_Wrt, nullptr, 128,128, T2h,T2l);
  tsplit_kernel<<<(128*128+255)/256,256,0,stream>>>(g2_Wr,  nullptr, 128,128, T3h,T3l);
  tsplit_kernel<<<(128*128+255)/256,256,0,stream>>>(g2_Wrt, nullptr, 128,128, T4h,T4l);
  tsplit_kernel<<<(64*128 +255)/256,256,0,stream>>>(d1_Wr,  nullptr, 64,128,  T5h,T5l);
  tsplit_kernel<<<(64*128 +255)/256,256,0,stream>>>(d1_Wrt, nullptr, 64,128,  T6h,T6l);
  tsplit_kernel<<<(256*256+255)/256,256,0,stream>>>(c1_Wr,  nullptr, 256,256, T7h,T7l);
  tsplit_kernel<<<(256*256+255)/256,256,0,stream>>>(c1_Wrt, skip_W,  256,256, T8h,T8l);

  const int GB = (NN+127)/128;   // 391

  // ---- g1 ----
  gather_kernel<128><<<(NN*16+255)/256,256,0,stream>>>(XM16,128, PTR1,ESW1, AGh,AGl,128);
  mfma_gemm_kernel<true><<<dim3(GB,1),256,0,stream>>>(AGh,AGl,128, T1h,T1l, XM16,128, T2h,T2l,
                                                      g1_br, nullptr, nullptr, F116, 128, 0);
  // ---- g2 ----
  gather_kernel<128><<<(NN*16+255)/256,256,0,stream>>>(F116,128, PTR1,ESW1, AGh,AGl,128);
  mfma_gemm_kernel<true><<<dim3(GB,1),256,0,stream>>>(AGh,AGl,128, T3h,T3l, F116,128, T4h,T4l,
                                                      g2_br, nullptr, nullptr, XC16, 256, 0);
  // ---- duration branch -> XC cols 128..255 ----
  gather_kernel<64><<<(NN*8+255)/256,256,0,stream>>>(DX16,64, PTR2,ESW2, AGh,AGl,64);
  mfma_gemm_kernel<true><<<dim3(GB,1),256,0,stream>>>(AGh,AGl,64, T5h,T5l, DX16,64, T6h,T6l,
                                                      d1_br, nullptr, nullptr, XC16, 256, 128);
  // ---- c1 + folded skip ----
  gather_kernel<256><<<(NN*32+255)/256,256,0,stream>>>(XC16,256, PTR1,ESW1, AGh,AGl,256);
  mfma_gemm_kernel<false><<<dim3(GB,2),256,0,stream>>>(AGh,AGl,256, T7h,T7l, XC16,256, T8h,T8l,
                                                       c1_br, skip_b, XC2, nullptr, 256, 0);
  // ---- pool (two-phase) ----
  hipMemsetAsync(EMBS, 0, (size_t)BB*256*4, stream);
  pool_partial_kernel<<<GB,256,0,stream>>>(XC2, batch, EMBS);
  pool_final_kernel<<<BB,256,0,stream>>>(EMBS, batch, EMB);
  // ---- seq / head ----
  seq_kernel<<<BB,256,0,stream>>>(seq, fc1_W, fc1_b, fc2_W, fc2_b, S2B);
  head_kernel<<<BB,256,0,stream>>>(EMB, S2B, fcc_W, fcc_b, cls_W, cls_b, out);
}

// Round 4
// 573.135 us; speedup vs baseline: 3.1260x; 1.3390x over previous
//
#include <hip/hip_runtime.h>

#define NN 50000
#define MP 50176   // row-padded (multiple of 128)
#define EE 800000
#define BB 64
#define SCB 196    // scan blocks per graph: ceil(NN/256)

typedef _Float16 half_t;
typedef __attribute__((ext_vector_type(8))) _Float16 h16x8;
typedef __attribute__((ext_vector_type(8))) __bf16 bf16x8;
typedef __attribute__((ext_vector_type(4))) float f32x4;
typedef __attribute__((ext_vector_type(8))) unsigned short u16x8;

__device__ __forceinline__ float bu2f(unsigned short u){
  union { unsigned u32; float f; } c; c.u32 = ((unsigned)u) << 16; return c.f;
}
__device__ __forceinline__ unsigned short f2bu(float f){
  union { __bf16 h; unsigned short u; } c; c.h = (__bf16)f; return c.u;
}

// ---------------- fp32 rows -> fp16 rows (optional -1 masking) ----------------
template<bool MASK>
__global__ __launch_bounds__(256)
void tohalf_kernel(const float* __restrict__ x, half_t* __restrict__ o, int n8){
  int i = blockIdx.x*blockDim.x + threadIdx.x;
  if (i >= n8) return;
  float4 a = ((const float4*)x)[2*i];
  float4 b = ((const float4*)x)[2*i+1];
  float v[8] = {a.x,a.y,a.z,a.w,b.x,b.y,b.z,b.w};
  h16x8 h;
  #pragma unroll
  for (int j=0;j<8;j++){
    float f = v[j];
    if (MASK && f == -1.0f) f = 0.f;
    h[j] = (half_t)f;
  }
  ((h16x8*)o)[i] = h;
}

// ---------------- transpose + split weights: W[K][N](+add) -> Wt[N][K] hi/lo ----------------
__global__ __launch_bounds__(256)
void tsplit_kernel(const float* __restrict__ W, const float* __restrict__ add,
                   int K, int N, unsigned short* __restrict__ oh, unsigned short* __restrict__ ol){
  int i = blockIdx.x*blockDim.x + threadIdx.x;
  if (i >= K*N) return;
  int k = i / N, n = i - k*N;
  float v = W[i] + (add ? add[i] : 0.f);
  unsigned short hu = f2bu(v);
  oh[(size_t)n*K + k] = hu;
  ol[(size_t)n*K + k] = f2bu(v - bu2f(hu));
}

// ---------------- CSR build (both graphs fused) ----------------
__global__ __launch_bounds__(256)
void count2_kernel(const int* __restrict__ dst1, const int* __restrict__ dst2,
                   int* __restrict__ cnt){
  int i = blockIdx.x*blockDim.x + threadIdx.x;
  if (i < EE){
    atomicAdd(&cnt[dst1[i]], 1);
    atomicAdd(&cnt[NN + dst2[i]], 1);
  }
}

__global__ __launch_bounds__(256)
void scan_local_kernel(const int* __restrict__ cnt, int* __restrict__ ptr, int* __restrict__ bsum){
  int g = blockIdx.y, blk = blockIdx.x, t = threadIdx.x;
  int i = blk*256 + t;
  int v = (i < NN) ? cnt[g*NN + i] : 0;
  __shared__ int s[256];
  s[t] = v; __syncthreads();
  #pragma unroll
  for (int off=1; off<256; off<<=1){
    int u = (t>=off)? s[t-off] : 0;
    __syncthreads(); s[t] += u; __syncthreads();
  }
  if (i < NN) ptr[g*(NN+1) + i] = s[t] - v;   // local exclusive
  if (t == 255) bsum[g*SCB + blk] = s[255];
}

__global__ __launch_bounds__(256)
void scan_bsum_kernel(int* __restrict__ bsum, int* __restrict__ ptr){
  int g = blockIdx.x, t = threadIdx.x;
  int v = (t < SCB) ? bsum[g*SCB + t] : 0;
  __shared__ int s[256];
  s[t] = v; __syncthreads();
  #pragma unroll
  for (int off=1; off<256; off<<=1){
    int u = (t>=off)? s[t-off] : 0;
    __syncthreads(); s[t] += u; __syncthreads();
  }
  if (t < SCB) bsum[g*SCB + t] = s[t] - v;    // exclusive block offsets
  if (t == 255) ptr[g*(NN+1) + NN] = s[255];
}

__global__ __launch_bounds__(256)
void scan_add_kernel(int* __restrict__ ptr, const int* __restrict__ bsum, int* __restrict__ cur){
  int g = blockIdx.y, blk = blockIdx.x, t = threadIdx.x;
  int i = blk*256 + t;
  if (i < NN){
    int v = ptr[g*(NN+1) + i] + bsum[g*SCB + blk];
    ptr[g*(NN+1) + i] = v;
    cur[g*NN + i] = v;
  }
}

__global__ __launch_bounds__(256)
void fill2_kernel(const int* __restrict__ src1, const int* __restrict__ dst1, const float* __restrict__ ea,
                  const int* __restrict__ src2, const int* __restrict__ dst2, const float* __restrict__ dea,
                  int* __restrict__ cur, int2* __restrict__ esw1, int2* __restrict__ esw2){
  int i = blockIdx.x*blockDim.x + threadIdx.x;
  if (i < EE){
    int p = atomicAdd(&cur[dst1[i]], 1);
    esw1[p] = make_int2(src1[i], __float_as_int(ea[i]));
    int q = atomicAdd(&cur[NN + dst2[i]], 1);
    esw2[q] = make_int2(src2[i], __float_as_int(dea[i]));
  }
}

// ---------------- CSR gather on fp16 rows, split-bf16 output ----------------
template<int F>
__global__ __launch_bounds__(256)
void gather_kernel(const half_t* __restrict__ H, int ldh,
                   const int* __restrict__ ptr, const int2* __restrict__ esw,
                   unsigned short* __restrict__ Oh, unsigned short* __restrict__ Ol, int ldo){
  const int L = F/8;
  int gt = blockIdx.x*blockDim.x + threadIdx.x;
  int node = gt / L, lane = gt - node*L;
  if (node >= NN) return;
  int lo = ptr[node], hi = ptr[node+1];
  float acc[8] = {0,0,0,0,0,0,0,0};
  int p = lo;
  #pragma unroll 1
  for (; p+4 <= hi; p += 4){
    int2 e0 = esw[p], e1 = esw[p+1], e2 = esw[p+2], e3 = esw[p+3];
    h16x8 v0 = *(const h16x8*)(H + (size_t)e0.x*ldh + lane*8);
    h16x8 v1 = *(const h16x8*)(H + (size_t)e1.x*ldh + lane*8);
    h16x8 v2 = *(const h16x8*)(H + (size_t)e2.x*ldh + lane*8);
    h16x8 v3 = *(const h16x8*)(H + (size_t)e3.x*ldh + lane*8);
    float w0 = __int_as_float(e0.y), w1 = __int_as_float(e1.y);
    float w2 = __int_as_float(e2.y), w3 = __int_as_float(e3.y);
    #pragma unroll
    for (int j=0;j<8;j++)
      acc[j] += w0*(float)v0[j] + w1*(float)v1[j] + w2*(float)v2[j] + w3*(float)v3[j];
  }
  for (; p < hi; ++p){
    int2 e = esw[p];
    h16x8 v = *(const h16x8*)(H + (size_t)e.x*ldh + lane*8);
    float w = __int_as_float(e.y);
    #pragma unroll
    for (int j=0;j<8;j++) acc[j] += w*(float)v[j];
  }
  u16x8 oh, ol;
  #pragma unroll
  for (int j=0;j<8;j++){
    unsigned short hu = f2bu(acc[j]);
    oh[j] = hu;
    ol[j] = f2bu(acc[j] - bu2f(hu));
  }
  *(u16x8*)(Oh + (size_t)node*ldo + lane*8) = oh;
  *(u16x8*)(Ol + (size_t)node*ldo + lane*8) = ol;
}

// ---------------- split-bf16 MFMA dual GEMM ----------------
__device__ __forceinline__ int lds_off(int r, int slot){ return r*64 + ((slot ^ (r&7))<<3); }

template<bool OUT16>
__global__ __launch_bounds__(256,2)
void mfma_gemm_kernel(const unsigned short* __restrict__ Ah, const unsigned short* __restrict__ Al, int K1,
                      const unsigned short* __restrict__ W1h, const unsigned short* __restrict__ W1l,
                      const half_t* __restrict__ Rf, int K2,
                      const unsigned short* __restrict__ W2h, const unsigned short* __restrict__ W2l,
                      const float* __restrict__ b1, const float* __restrict__ b2,
                      float* __restrict__ outf, half_t* __restrict__ out16, int ldo, int coloff){
  __shared__ unsigned short sAh[128*64], sAl[128*64], sBh[128*64], sBl[128*64];
  const int tid  = threadIdx.x;
  const int lane = tid & 63;
  const int wave = tid >> 6;
  const int wr = (wave>>1)*64, wc = (wave&1)*64;
  const int row0 = blockIdx.x*128;
  const int col0 = blockIdx.y*128;

  f32x4 acc[4][4];
  #pragma unroll
  for (int a=0;a<4;a++)
    #pragma unroll
    for (int b=0;b<4;b++){ acc[a][b][0]=0.f; acc[a][b][1]=0.f; acc[a][b][2]=0.f; acc[a][b][3]=0.f; }

  #pragma unroll 1
  for (int pass=0; pass<2; ++pass){
    const unsigned short* Bhp = pass ? W2h : W1h;
    const unsigned short* Blp = pass ? W2l : W1l;
    const int K = pass ? K2 : K1;
    #pragma unroll 1
    for (int k0=0; k0<K; k0+=64){
      __syncthreads();
      #pragma unroll
      for (int i=0;i<4;i++){
        int c = tid + i*256;
        int r = c >> 3, s = c & 7;
        int lo = lds_off(r, s);
        size_t gb = (size_t)(col0+r)*K + k0 + s*8;
        *(u16x8*)&sBh[lo] = *(const u16x8*)(Bhp + gb);
        *(u16x8*)&sBl[lo] = *(const u16x8*)(Blp + gb);
        if (pass == 0){
          size_t ga = (size_t)(row0+r)*K1 + k0 + s*8;
          *(u16x8*)&sAh[lo] = *(const u16x8*)(Ah + ga);
          *(u16x8*)&sAl[lo] = *(const u16x8*)(Al + ga);
        } else {
          h16x8 v = *(const h16x8*)(Rf + (size_t)(row0+r)*K2 + k0 + s*8);
          u16x8 hh, ll;
          #pragma unroll
          for (int j=0;j<8;j++){
            float f = (float)v[j];
            unsigned short hu = f2bu(f);
            hh[j] = hu;
            ll[j] = f2bu(f - bu2f(hu));
          }
          *(u16x8*)&sAh[lo] = hh;
          *(u16x8*)&sAl[lo] = ll;
        }
      }
      __syncthreads();
      #pragma unroll
      for (int ks=0; ks<2; ++ks){
        const int rsel = lane >> 4;
        bf16x8 ahf[4], alf[4];
        #pragma unroll
        for (int mf=0; mf<4; mf++){
          int r = wr + mf*16 + (lane&15);
          int off = lds_off(r, ks*4 + rsel);
          ahf[mf] = *(const bf16x8*)&sAh[off];
          alf[mf] = *(const bf16x8*)&sAl[off];
        }
        #pragma unroll
        for (int nf=0; nf<4; nf++){
          int cix = wc + nf*16 + (lane&15);
          int off = lds_off(cix, ks*4 + rsel);
          bf16x8 bh = *(const bf16x8*)&sBh[off];
          bf16x8 bl = *(const bf16x8*)&sBl[off];
          #pragma unroll
          for (int mf=0; mf<4; mf++){
            acc[mf][nf] = __builtin_amdgcn_mfma_f32_16x16x32_bf16(ahf[mf], bh, acc[mf][nf], 0,0,0);
            acc[mf][nf] = __builtin_amdgcn_mfma_f32_16x16x32_bf16(alf[mf], bh, acc[mf][nf], 0,0,0);
            acc[mf][nf] = __builtin_amdgcn_mfma_f32_16x16x32_bf16(ahf[mf], bl, acc[mf][nf], 0,0,0);
          }
        }
      }
    }
  }

  #pragma unroll
  for (int nf=0; nf<4; nf++){
    int colg = col0 + wc + nf*16 + (lane&15);
    float bias = b1[colg] + (b2 ? b2[colg] : 0.f);
    #pragma unroll
    for (int mf=0; mf<4; mf++){
      #pragma unroll
      for (int r=0; r<4; r++){
        int rowg = row0 + wr + mf*16 + (lane>>4)*4 + r;
        if (rowg < NN){
          float o = fmaxf(acc[mf][nf][r] + bias, 0.f);
          if (OUT16) out16[(size_t)rowg*ldo + coloff + colg] = (half_t)o;
          else       outf [(size_t)rowg*ldo + coloff + colg] = o;
        }
      }
    }
  }
}

// ---------------- two-phase mean pool (batch sorted) ----------------
__global__ __launch_bounds__(256)
void pool_partial_kernel(const float* __restrict__ xc2, const int* __restrict__ batch,
                         float* __restrict__ sums){
  int r0 = blockIdx.x*128;
  int r1 = r0 + 128; if (r1 > NN) r1 = NN;
  int t = threadIdx.x;
  float run = 0.f;
  int cb = batch[r0];
  for (int r=r0; r<r1; ++r){
    int b = batch[r];
    if (b != cb){ atomicAdd(&sums[cb*256 + t], run); run = 0.f; cb = b; }
    run += xc2[(size_t)r*256 + t];
  }
  atomicAdd(&sums[cb*256 + t], run);
}

__device__ __forceinline__ int lower_bound_i(const int* __restrict__ arr, int n, int v){
  int lo=0, hi=n;
  while (lo < hi){ int mid=(lo+hi)>>1; if (arr[mid] < v) lo=mid+1; else hi=mid; }
  return lo;
}

__global__ __launch_bounds__(256)
void pool_final_kernel(const float* __restrict__ sums, const int* __restrict__ batch,
                       float* __restrict__ emb){
  int b = blockIdx.x, t = threadIdx.x;
  int lo = lower_bound_i(batch, NN, b);
  int hi = lower_bound_i(batch, NN, b+1);
  emb[b*256 + t] = sums[b*256 + t] / fmaxf((float)(hi-lo), 1.0f);
}

// ---------------- sequence MLP ----------------
__global__ __launch_bounds__(256)
void seq_kernel(const float* __restrict__ seq,
                const float* __restrict__ W1, const float* __restrict__ b1,
                const float* __restrict__ W2, const float* __restrict__ b2,
                float* __restrict__ s2){
  __shared__ float sin_[256], s1[256];
  int b = blockIdx.x, t = threadIdx.x;
  sin_[t] = seq[b*256 + t];
  __syncthreads();
  float a = b1[t];
  for (int k=0;k<256;k++) a += sin_[k]*W1[k*256 + t];
  s1[t] = fmaxf(a, 0.f);
  __syncthreads();
  if (t < 128){
    float a2 = b2[t];
    for (int k=0;k<256;k++) a2 += s1[k]*W2[k*128 + t];
    s2[b*128 + t] = fmaxf(a2, 0.f);
  }
}

// ---------------- fused head ----------------
__global__ __launch_bounds__(256)
void head_kernel(const float* __restrict__ emb, const float* __restrict__ s2,
                 const float* __restrict__ fccW, const float* __restrict__ fccb,
                 const float* __restrict__ clsW, const float* __restrict__ clsb,
                 float* __restrict__ out){
  __shared__ float h[384], h2[256], lg[16];
  __shared__ float mred, lred;
  int b = blockIdx.x, t = threadIdx.x;
  h[t] = emb[b*256 + t];
  if (t < 128) h[256 + t] = s2[b*128 + t];
  __syncthreads();
  float a = fccb[t];
  for (int k=0;k<384;k++) a += h[k]*fccW[k*256 + t];
  h2[t] = fmaxf(a, 0.f);
  __syncthreads();
  if (t < 16){
    float a2 = clsb[t];
    for (int k=0;k<256;k++) a2 += h2[k]*clsW[k*16 + t];
    lg[t] = a2;
  }
  __syncthreads();
  if (t == 0){
    float m = lg[0];
    for (int i=1;i<16;i++) m = fmaxf(m, lg[i]);
    float s = 0.f;
    for (int i=0;i<16;i++) s += expf(lg[i]-m);
    mred = m; lred = logf(s);
  }
  __syncthreads();
  if (t < 16) out[b*16 + t] = lg[t] - mred - lred;
}

extern "C" void kernel_launch(void* const* d_in, const int* in_sizes, int n_in,
                              void* d_out, int out_size, void* d_ws, size_t ws_size,
                              hipStream_t stream){
  const float* x      = (const float*)d_in[0];
  const int*   ei     = (const int*)  d_in[1];
  const float* ea     = (const float*)d_in[2];
  const int*   batch  = (const int*)  d_in[3];
  const float* dx     = (const float*)d_in[4];
  const int*   dei    = (const int*)  d_in[5];
  const float* dea    = (const float*)d_in[6];
  const float* seq    = (const float*)d_in[7];
  const float* g1_Wr  = (const float*)d_in[8];
  const float* g1_br  = (const float*)d_in[9];
  const float* g1_Wrt = (const float*)d_in[10];
  const float* g2_Wr  = (const float*)d_in[11];
  const float* g2_br  = (const float*)d_in[12];
  const float* g2_Wrt = (const float*)d_in[13];
  const float* d1_Wr  = (const float*)d_in[14];
  const float* d1_br  = (const float*)d_in[15];
  const float* d1_Wrt = (const float*)d_in[16];
  const float* c1_Wr  = (const float*)d_in[17];
  const float* c1_br  = (const float*)d_in[18];
  const float* c1_Wrt = (const float*)d_in[19];
  const float* skip_W = (const float*)d_in[20];
  const float* skip_b = (const float*)d_in[21];
  const float* fc1_W  = (const float*)d_in[22];
  const float* fc1_b  = (const float*)d_in[23];
  const float* fc2_W  = (const float*)d_in[24];
  const float* fc2_b  = (const float*)d_in[25];
  const float* fcc_W  = (const float*)d_in[26];
  const float* fcc_b  = (const float*)d_in[27];
  const float* cls_W  = (const float*)d_in[28];
  const float* cls_b  = (const float*)d_in[29];
  float* out = (float*)d_out;

  char* wp = (char*)d_ws;
  auto alloc = [&](size_t bytes)->char*{
    char* p = wp; wp += (bytes + 255) & ~(size_t)255; return p;
  };
  half_t* XM16 = (half_t*)alloc((size_t)MP*128*2);
  half_t* F116 = (half_t*)alloc((size_t)MP*128*2);
  half_t* DX16 = (half_t*)alloc((size_t)MP*64*2);
  half_t* XC16 = (half_t*)alloc((size_t)MP*256*2);
  unsigned short* AGh = (unsigned short*)alloc((size_t)MP*256*2);
  unsigned short* AGl = (unsigned short*)alloc((size_t)MP*256*2);
  float* XC2 = (float*)alloc((size_t)MP*256*4);
  // transposed split weights
  unsigned short* T1h = (unsigned short*)alloc(128*128*2); unsigned short* T1l = (unsigned short*)alloc(128*128*2);
  unsigned short* T2h = (unsigned short*)alloc(128*128*2); unsigned short* T2l = (unsigned short*)alloc(128*128*2);
  unsigned short* T3h = (unsigned short*)alloc(128*128*2); unsigned short* T3l = (unsigned short*)alloc(128*128*2);
  unsigned short* T4h = (unsigned short*)alloc(128*128*2); unsigned short* T4l = (unsigned short*)alloc(128*128*2);
  unsigned short* T5h = (unsigned short*)alloc(64*128*2);  unsigned short* T5l = (unsigned short*)alloc(64*128*2);
  unsigned short* T6h = (unsigned short*)alloc(64*128*2);  unsigned short* T6l = (unsigned short*)alloc(64*128*2);
  unsigned short* T7h = (unsigned short*)alloc(256*256*2); unsigned short* T7l = (unsigned short*)alloc(256*256*2);
  unsigned short* T8h = (unsigned short*)alloc(256*256*2); unsigned short* T8l = (unsigned short*)alloc(256*256*2);
  // CSR (both graphs)
  int*  PTR  = (int*)alloc((size_t)2*(NN+1)*4);
  int*  PTR1 = PTR;
  int*  PTR2 = PTR + (NN+1);
  int2* ESW1 = (int2*)alloc((size_t)EE*8);
  int2* ESW2 = (int2*)alloc((size_t)EE*8);
  int*  CNT  = (int*)alloc((size_t)2*NN*4);
  int*  CUR  = (int*)alloc((size_t)2*NN*4);
  int*  BSUM = (int*)alloc((size_t)2*SCB*4);
  float* EMBS = (float*)alloc((size_t)BB*256*4);
  float* EMB  = (float*)alloc((size_t)BB*256*4);
  float* S2B  = (float*)alloc((size_t)BB*128*4);

  const int* src1 = ei;  const int* dst1 = ei + EE;
  const int* src2 = dei; const int* dst2 = dei + EE;
  const int eb = (EE+255)/256;

  // CSR build (both graphs fused)
  hipMemsetAsync(CNT, 0, (size_t)2*NN*4, stream);
  count2_kernel<<<eb,256,0,stream>>>(dst1, dst2, CNT);
  scan_local_kernel<<<dim3(SCB,2),256,0,stream>>>(CNT, PTR, BSUM);
  scan_bsum_kernel<<<2,256,0,stream>>>(BSUM, PTR);
  scan_add_kernel<<<dim3(SCB,2),256,0,stream>>>(PTR, BSUM, CUR);
  fill2_kernel<<<eb,256,0,stream>>>(src1,dst1,ea, src2,dst2,dea, CUR, ESW1, ESW2);

  // fp16 activations
  tohalf_kernel<true ><<<(NN*16+255)/256,256,0,stream>>>(x,  XM16, NN*16);
  tohalf_kernel<false><<<(NN*8 +255)/256,256,0,stream>>>(dx, DX16, NN*8);

  // weight prep (transpose + split; T8 = c1_Wroot + skip_W)
  tsplit_kernel<<<(128*128+255)/256,256,0,stream>>>(g1_Wr,  nullptr, 128,128, T1h,T1l);
  tsplit_kernel<<<(128*128+255)/256,256,0,stream>>>(g1_Wrt, nullptr, 128,128, T2h,T2l);
  tsplit_kernel<<<(128*128+255)/256,256,0,stream>>>(g2_Wr,  nullptr, 128,128, T3h,T3l);
  tsplit_kernel<<<(128*128+255)/256,256,0,stream>>>(g2_Wrt, nullptr, 128,128, T4h,T4l);
  tsplit_kernel<<<(64*128 +255)/256,256,0,stream>>>(d1_Wr,  nullptr, 64,128,  T5h,T5l);
  tsplit_kernel<<<(64*128 +255)/256,256,0,stream>>>(d1_Wrt, nullptr, 64,128,  T6h,T6l);
  tsplit_kernel<<<(256*256+255)/256,256,0,stream>>>(c1_Wr,  nullptr, 256,256, T7h,T7l);
  tsplit_kernel<<<(256*256+255)/256,256,0,stream>>>(c1_Wrt, skip_W,  256,256, T8h,T8l);

  const int GB = (NN+127)/128;   // 391

  // ---- g1 ----
  gather_kernel<128><<<(NN*16+255)/256,256,0,stream>>>(XM16,128, PTR1,ESW1, AGh,AGl,128);
  mfma_gemm_kernel<true><<<dim3(GB,1),256,0,stream>>>(AGh,AGl,128, T1h,T1l, XM16,128, T2h,T2l,
                                                      g1_br, nullptr, nullptr, F116, 128, 0);
  // ---- g2 ----
  gather_kernel<128><<<(NN*16+255)/256,256,0,stream>>>(F116,128, PTR1,ESW1, AGh,AGl,128);
  mfma_gemm_kernel<true><<<dim3(GB,1),256,0,stream>>>(AGh,AGl,128, T3h,T3l, F116,128, T4h,T4l,
                                                      g2_br, nullptr, nullptr, XC16, 256, 0);
  // ---- duration branch -> XC cols 128..255 ----
  gather_kernel<64><<<(NN*8+255)/256,256,0,stream>>>(DX16,64, PTR2,ESW2, AGh,AGl,64);
  mfma_gemm_kernel<true><<<dim3(GB,1),256,0,stream>>>(AGh,AGl,64, T5h,T5l, DX16,64, T6h,T6l,
                                                      d1_br, nullptr, nullptr, XC16, 256, 128);
  // ---- c1 + folded skip ----
  gather_kernel<256><<<(NN*32+255)/256,256,0,stream>>>(XC16,256, PTR1,ESW1, AGh,AGl,256);
  mfma_gemm_kernel<false><<<dim3(GB,2),256,0,stream>>>(AGh,AGl,256, T7h,T7l, XC16,256, T8h,T8l,
                                                       c1_br, skip_b, XC2, nullptr, 256, 0);
  // ---- pool (two-phase) ----
  hipMemsetAsync(EMBS, 0, (size_t)BB*256*4, stream);
  pool_partial_kernel<<<GB,256,0,stream>>>(XC2, batch, EMBS);
  pool_final_kernel<<<BB,256,0,stream>>>(EMBS, batch, EMB);
  // ---- seq / head ----
  seq_kernel<<<BB,256,0,stream>>>(seq, fc1_W, fc1_b, fc2_W, fc2_b, S2B);
  head_kernel<<<BB,256,0,stream>>>(EMB, S2B, fcc_W, fcc_b, cls_W, cls_b, out);
}

// Round 5
// 506.121 us; speedup vs baseline: 3.5399x; 1.1324x over previous
//
#include <hip/hip_runtime.h>

#define NN 50000
#define MP 50176   // row-padded (multiple of 128)
#define EE 800000
#define BB 64
#define SCB 196    // scan blocks per graph: ceil(NN/256)
#define NSLICE 8
#define SLICEN (NN/NSLICE)   // 6250

typedef _Float16 half_t;
typedef __attribute__((ext_vector_type(8))) _Float16 h16x8;
typedef __attribute__((ext_vector_type(8))) __bf16 bf16x8;
typedef __attribute__((ext_vector_type(4))) float f32x4;
typedef __attribute__((ext_vector_type(8))) unsigned short u16x8;

__device__ __forceinline__ float bu2f(unsigned short u){
  union { unsigned u32; float f; } c; c.u32 = ((unsigned)u) << 16; return c.f;
}
__device__ __forceinline__ unsigned short f2bu(float f){
  union { __bf16 h; unsigned short u; } c; c.h = (__bf16)f; return c.u;
}

// ---------------- fp32 rows -> fp16 rows (optional -1 masking) ----------------
template<bool MASK>
__global__ __launch_bounds__(256)
void tohalf_kernel(const float* __restrict__ x, half_t* __restrict__ o, int n8){
  int i = blockIdx.x*blockDim.x + threadIdx.x;
  if (i >= n8) return;
  float4 a = ((const float4*)x)[2*i];
  float4 b = ((const float4*)x)[2*i+1];
  float v[8] = {a.x,a.y,a.z,a.w,b.x,b.y,b.z,b.w};
  h16x8 h;
  #pragma unroll
  for (int j=0;j<8;j++){
    float f = v[j];
    if (MASK && f == -1.0f) f = 0.f;
    h[j] = (half_t)f;
  }
  ((h16x8*)o)[i] = h;
}

// ---------------- fused transpose+split for all 8 weights ----------------
struct TS { const float* W; const float* add; unsigned short* oh; unsigned short* ol; int K; int N; int base; };
struct TS8 { TS t[8]; int total; };

__global__ __launch_bounds__(256)
void tsplit8_kernel(TS8 a){
  int i = blockIdx.x*256 + threadIdx.x;
  if (i >= a.total) return;
  int w = 0;
  #pragma unroll
  for (int j=1;j<8;j++) if (i >= a.t[j].base) w = j;
  TS ts = a.t[w];
  int e = i - ts.base;
  int k = e / ts.N, n = e - k*ts.N;
  float v = ts.W[e] + (ts.add ? ts.add[e] : 0.f);
  unsigned short hu = f2bu(v);
  ts.oh[(size_t)n*ts.K + k] = hu;
  ts.ol[(size_t)n*ts.K + k] = f2bu(v - bu2f(hu));
}

// ---------------- CSR build (both graphs, XCD-sliced) ----------------
__global__ __launch_bounds__(256)
void count2x_kernel(const int* __restrict__ dst1, const int* __restrict__ dst2,
                    int* __restrict__ cnt){
  int slice = blockIdx.x & (NSLICE-1);
  int i = (blockIdx.x >> 3)*256 + threadIdx.x;
  int lo = slice*SLICEN, hi = lo + SLICEN;
  if (i < EE){
    int d1 = dst1[i];
    if (d1 >= lo && d1 < hi) atomicAdd(&cnt[d1], 1);
    int d2 = dst2[i];
    if (d2 >= lo && d2 < hi) atomicAdd(&cnt[NN + d2], 1);
  }
}

__global__ __launch_bounds__(256)
void scan_local_kernel(const int* __restrict__ cnt, int* __restrict__ ptr, int* __restrict__ bsum){
  int g = blockIdx.y, blk = blockIdx.x, t = threadIdx.x;
  int i = blk*256 + t;
  int v = (i < NN) ? cnt[g*NN + i] : 0;
  __shared__ int s[256];
  s[t] = v; __syncthreads();
  #pragma unroll
  for (int off=1; off<256; off<<=1){
    int u = (t>=off)? s[t-off] : 0;
    __syncthreads(); s[t] += u; __syncthreads();
  }
  if (i < NN) ptr[g*(NN+1) + i] = s[t] - v;   // local exclusive
  if (t == 255) bsum[g*SCB + blk] = s[255];
}

__global__ __launch_bounds__(256)
void scan_bsum_kernel(int* __restrict__ bsum, int* __restrict__ ptr){
  int g = blockIdx.x, t = threadIdx.x;
  int v = (t < SCB) ? bsum[g*SCB + t] : 0;
  __shared__ int s[256];
  s[t] = v; __syncthreads();
  #pragma unroll
  for (int off=1; off<256; off<<=1){
    int u = (t>=off)? s[t-off] : 0;
    __syncthreads(); s[t] += u; __syncthreads();
  }
  if (t < SCB) bsum[g*SCB + t] = s[t] - v;    // exclusive block offsets
  if (t == 255) ptr[g*(NN+1) + NN] = s[255];
}

__global__ __launch_bounds__(256)
void scan_add_kernel(int* __restrict__ ptr, const int* __restrict__ bsum, int* __restrict__ cur){
  int g = blockIdx.y, blk = blockIdx.x, t = threadIdx.x;
  int i = blk*256 + t;
  if (i < NN){
    int v = ptr[g*(NN+1) + i] + bsum[g*SCB + blk];
    ptr[g*(NN+1) + i] = v;
    cur[g*NN + i] = v;
  }
}

__global__ __launch_bounds__(256)
void fill2x_kernel(const int* __restrict__ src1, const int* __restrict__ dst1, const float* __restrict__ ea,
                   const int* __restrict__ src2, const int* __restrict__ dst2, const float* __restrict__ dea,
                   int* __restrict__ cur, int2* __restrict__ esw1, int2* __restrict__ esw2){
  int slice = blockIdx.x & (NSLICE-1);
  int i = (blockIdx.x >> 3)*256 + threadIdx.x;
  int lo = slice*SLICEN, hi = lo + SLICEN;
  if (i < EE){
    int d1 = dst1[i];
    if (d1 >= lo && d1 < hi){
      int p = atomicAdd(&cur[d1], 1);
      esw1[p] = make_int2(src1[i], __float_as_int(ea[i]));
    }
    int d2 = dst2[i];
    if (d2 >= lo && d2 < hi){
      int q = atomicAdd(&cur[NN + d2], 1);
      esw2[q] = make_int2(src2[i], __float_as_int(dea[i]));
    }
  }
}

// ---------------- CSR gather on fp16 rows, split-bf16 output ----------------
template<int F>
__global__ __launch_bounds__(256)
void gather_kernel(const half_t* __restrict__ H, int ldh,
                   const int* __restrict__ ptr, const int2* __restrict__ esw,
                   unsigned short* __restrict__ Oh, unsigned short* __restrict__ Ol, int ldo){
  const int L = F/8;
  int gt = blockIdx.x*blockDim.x + threadIdx.x;
  int node = gt / L, lane = gt - node*L;
  if (node >= NN) return;
  int lo = ptr[node], hi = ptr[node+1];
  float acc[8] = {0,0,0,0,0,0,0,0};
  int p = lo;
  #pragma unroll 1
  for (; p+4 <= hi; p += 4){
    int2 e0 = esw[p], e1 = esw[p+1], e2 = esw[p+2], e3 = esw[p+3];
    h16x8 v0 = *(const h16x8*)(H + (size_t)e0.x*ldh + lane*8);
    h16x8 v1 = *(const h16x8*)(H + (size_t)e1.x*ldh + lane*8);
    h16x8 v2 = *(const h16x8*)(H + (size_t)e2.x*ldh + lane*8);
    h16x8 v3 = *(const h16x8*)(H + (size_t)e3.x*ldh + lane*8);
    float w0 = __int_as_float(e0.y), w1 = __int_as_float(e1.y);
    float w2 = __int_as_float(e2.y), w3 = __int_as_float(e3.y);
    #pragma unroll
    for (int j=0;j<8;j++)
      acc[j] += w0*(float)v0[j] + w1*(float)v1[j] + w2*(float)v2[j] + w3*(float)v3[j];
  }
  for (; p < hi; ++p){
    int2 e = esw[p];
    h16x8 v = *(const h16x8*)(H + (size_t)e.x*ldh + lane*8);
    float w = __int_as_float(e.y);
    #pragma unroll
    for (int j=0;j<8;j++) acc[j] += w*(float)v[j];
  }
  u16x8 oh, ol;
  #pragma unroll
  for (int j=0;j<8;j++){
    unsigned short hu = f2bu(acc[j]);
    oh[j] = hu;
    ol[j] = f2bu(acc[j] - bu2f(hu));
  }
  *(u16x8*)(Oh + (size_t)node*ldo + lane*8) = oh;
  *(u16x8*)(Ol + (size_t)node*ldo + lane*8) = ol;
}

// ---------------- split-bf16 MFMA dual GEMM ----------------
__device__ __forceinline__ int lds_off(int r, int slot){ return r*64 + ((slot ^ (r&7))<<3); }

template<bool OUT16>
__global__ __launch_bounds__(256,2)
void mfma_gemm_kernel(const unsigned short* __restrict__ Ah, const unsigned short* __restrict__ Al, int K1,
                      const unsigned short* __restrict__ W1h, const unsigned short* __restrict__ W1l,
                      const half_t* __restrict__ Rf, int K2,
                      const unsigned short* __restrict__ W2h, const unsigned short* __restrict__ W2l,
                      const float* __restrict__ b1, const float* __restrict__ b2,
                      float* __restrict__ outf, half_t* __restrict__ out16, int ldo, int coloff){
  __shared__ unsigned short sAh[128*64], sAl[128*64], sBh[128*64], sBl[128*64];
  const int tid  = threadIdx.x;
  const int lane = tid & 63;
  const int wave = tid >> 6;
  const int wr = (wave>>1)*64, wc = (wave&1)*64;
  const int row0 = blockIdx.x*128;
  const int col0 = blockIdx.y*128;

  f32x4 acc[4][4];
  #pragma unroll
  for (int a=0;a<4;a++)
    #pragma unroll
    for (int b=0;b<4;b++){ acc[a][b][0]=0.f; acc[a][b][1]=0.f; acc[a][b][2]=0.f; acc[a][b][3]=0.f; }

  #pragma unroll 1
  for (int pass=0; pass<2; ++pass){
    const unsigned short* Bhp = pass ? W2h : W1h;
    const unsigned short* Blp = pass ? W2l : W1l;
    const int K = pass ? K2 : K1;
    #pragma unroll 1
    for (int k0=0; k0<K; k0+=64){
      __syncthreads();
      #pragma unroll
      for (int i=0;i<4;i++){
        int c = tid + i*256;
        int r = c >> 3, s = c & 7;
        int lo = lds_off(r, s);
        size_t gb = (size_t)(col0+r)*K + k0 + s*8;
        *(u16x8*)&sBh[lo] = *(const u16x8*)(Bhp + gb);
        *(u16x8*)&sBl[lo] = *(const u16x8*)(Blp + gb);
        if (pass == 0){
          size_t ga = (size_t)(row0+r)*K1 + k0 + s*8;
          *(u16x8*)&sAh[lo] = *(const u16x8*)(Ah + ga);
          *(u16x8*)&sAl[lo] = *(const u16x8*)(Al + ga);
        } else {
          h16x8 v = *(const h16x8*)(Rf + (size_t)(row0+r)*K2 + k0 + s*8);
          u16x8 hh, ll;
          #pragma unroll
          for (int j=0;j<8;j++){
            float f = (float)v[j];
            unsigned short hu = f2bu(f);
            hh[j] = hu;
            ll[j] = f2bu(f - bu2f(hu));
          }
          *(u16x8*)&sAh[lo] = hh;
          *(u16x8*)&sAl[lo] = ll;
        }
      }
      __syncthreads();
      #pragma unroll
      for (int ks=0; ks<2; ++ks){
        const int rsel = lane >> 4;
        bf16x8 ahf[4], alf[4];
        #pragma unroll
        for (int mf=0; mf<4; mf++){
          int r = wr + mf*16 + (lane&15);
          int off = lds_off(r, ks*4 + rsel);
          ahf[mf] = *(const bf16x8*)&sAh[off];
          alf[mf] = *(const bf16x8*)&sAl[off];
        }
        #pragma unroll
        for (int nf=0; nf<4; nf++){
          int cix = wc + nf*16 + (lane&15);
          int off = lds_off(cix, ks*4 + rsel);
          bf16x8 bh = *(const bf16x8*)&sBh[off];
          bf16x8 bl = *(const bf16x8*)&sBl[off];
          #pragma unroll
          for (int mf=0; mf<4; mf++){
            acc[mf][nf] = __builtin_amdgcn_mfma_f32_16x16x32_bf16(ahf[mf], bh, acc[mf][nf], 0,0,0);
            acc[mf][nf] = __builtin_amdgcn_mfma_f32_16x16x32_bf16(alf[mf], bh, acc[mf][nf], 0,0,0);
            acc[mf][nf] = __builtin_amdgcn_mfma_f32_16x16x32_bf16(ahf[mf], bl, acc[mf][nf], 0,0,0);
          }
        }
      }
    }
  }

  #pragma unroll
  for (int nf=0; nf<4; nf++){
    int colg = col0 + wc + nf*16 + (lane&15);
    float bias = b1[colg] + (b2 ? b2[colg] : 0.f);
    #pragma unroll
    for (int mf=0; mf<4; mf++){
      #pragma unroll
      for (int r=0; r<4; r++){
        int rowg = row0 + wr + mf*16 + (lane>>4)*4 + r;
        if (rowg < NN){
          float o = fmaxf(acc[mf][nf][r] + bias, 0.f);
          if (OUT16) out16[(size_t)rowg*ldo + coloff + colg] = (half_t)o;
          else       outf [(size_t)rowg*ldo + coloff + colg] = o;
        }
      }
    }
  }
}

// ---------------- two-phase mean pool (batch sorted) ----------------
__global__ __launch_bounds__(256)
void pool_partial_kernel(const float* __restrict__ xc2, const int* __restrict__ batch,
                         float* __restrict__ sums){
  int r0 = blockIdx.x*128;
  int r1 = r0 + 128; if (r1 > NN) r1 = NN;
  int t = threadIdx.x;
  float run = 0.f;
  int cb = batch[r0];
  for (int r=r0; r<r1; ++r){
    int b = batch[r];
    if (b != cb){ atomicAdd(&sums[cb*256 + t], run); run = 0.f; cb = b; }
    run += xc2[(size_t)r*256 + t];
  }
  atomicAdd(&sums[cb*256 + t], run);
}

__device__ __forceinline__ int lower_bound_i(const int* __restrict__ arr, int n, int v){
  int lo=0, hi=n;
  while (lo < hi){ int mid=(lo+hi)>>1; if (arr[mid] < v) lo=mid+1; else hi=mid; }
  return lo;
}

__global__ __launch_bounds__(256)
void pool_final_kernel(const float* __restrict__ sums, const int* __restrict__ batch,
                       float* __restrict__ emb){
  int b = blockIdx.x, t = threadIdx.x;
  int lo = lower_bound_i(batch, NN, b);
  int hi = lower_bound_i(batch, NN, b+1);
  emb[b*256 + t] = sums[b*256 + t] / fmaxf((float)(hi-lo), 1.0f);
}

// ---------------- sequence MLP ----------------
__global__ __launch_bounds__(256)
void seq_kernel(const float* __restrict__ seq,
                const float* __restrict__ W1, const float* __restrict__ b1,
                const float* __restrict__ W2, const float* __restrict__ b2,
                float* __restrict__ s2){
  __shared__ float sin_[256], s1[256];
  int b = blockIdx.x, t = threadIdx.x;
  sin_[t] = seq[b*256 + t];
  __syncthreads();
  float a = b1[t];
  for (int k=0;k<256;k++) a += sin_[k]*W1[k*256 + t];
  s1[t] = fmaxf(a, 0.f);
  __syncthreads();
  if (t < 128){
    float a2 = b2[t];
    for (int k=0;k<256;k++) a2 += s1[k]*W2[k*128 + t];
    s2[b*128 + t] = fmaxf(a2, 0.f);
  }
}

// ---------------- fused head ----------------
__global__ __launch_bounds__(256)
void head_kernel(const float* __restrict__ emb, const float* __restrict__ s2,
                 const float* __restrict__ fccW, const float* __restrict__ fccb,
                 const float* __restrict__ clsW, const float* __restrict__ clsb,
                 float* __restrict__ out){
  __shared__ float h[384], h2[256], lg[16];
  __shared__ float mred, lred;
  int b = blockIdx.x, t = threadIdx.x;
  h[t] = emb[b*256 + t];
  if (t < 128) h[256 + t] = s2[b*128 + t];
  __syncthreads();
  float a = fccb[t];
  for (int k=0;k<384;k++) a += h[k]*fccW[k*256 + t];
  h2[t] = fmaxf(a, 0.f);
  __syncthreads();
  if (t < 16){
    float a2 = clsb[t];
    for (int k=0;k<256;k++) a2 += h2[k]*clsW[k*16 + t];
    lg[t] = a2;
  }
  __syncthreads();
  if (t == 0){
    float m = lg[0];
    for (int i=1;i<16;i++) m = fmaxf(m, lg[i]);
    float s = 0.f;
    for (int i=0;i<16;i++) s += expf(lg[i]-m);
    mred = m; lred = logf(s);
  }
  __syncthreads();
  if (t < 16) out[b*16 + t] = lg[t] - mred - lred;
}

extern "C" void kernel_launch(void* const* d_in, const int* in_sizes, int n_in,
                              void* d_out, int out_size, void* d_ws, size_t ws_size,
                              hipStream_t stream){
  const float* x      = (const float*)d_in[0];
  const int*   ei     = (const int*)  d_in[1];
  const float* ea     = (const float*)d_in[2];
  const int*   batch  = (const int*)  d_in[3];
  const float* dx     = (const float*)d_in[4];
  const int*   dei    = (const int*)  d_in[5];
  const float* dea    = (const float*)d_in[6];
  const float* seq    = (const float*)d_in[7];
  const float* g1_Wr  = (const float*)d_in[8];
  const float* g1_br  = (const float*)d_in[9];
  const float* g1_Wrt = (const float*)d_in[10];
  const float* g2_Wr  = (const float*)d_in[11];
  const float* g2_br  = (const float*)d_in[12];
  const float* g2_Wrt = (const float*)d_in[13];
  const float* d1_Wr  = (const float*)d_in[14];
  const float* d1_br  = (const float*)d_in[15];
  const float* d1_Wrt = (const float*)d_in[16];
  const float* c1_Wr  = (const float*)d_in[17];
  const float* c1_br  = (const float*)d_in[18];
  const float* c1_Wrt = (const float*)d_in[19];
  const float* skip_W = (const float*)d_in[20];
  const float* skip_b = (const float*)d_in[21];
  const float* fc1_W  = (const float*)d_in[22];
  const float* fc1_b  = (const float*)d_in[23];
  const float* fc2_W  = (const float*)d_in[24];
  const float* fc2_b  = (const float*)d_in[25];
  const float* fcc_W  = (const float*)d_in[26];
  const float* fcc_b  = (const float*)d_in[27];
  const float* cls_W  = (const float*)d_in[28];
  const float* cls_b  = (const float*)d_in[29];
  float* out = (float*)d_out;

  char* wp = (char*)d_ws;
  auto alloc = [&](size_t bytes)->char*{
    char* p = wp; wp += (bytes + 255) & ~(size_t)255; return p;
  };
  half_t* XM16 = (half_t*)alloc((size_t)MP*128*2);
  half_t* F116 = (half_t*)alloc((size_t)MP*128*2);
  half_t* DX16 = (half_t*)alloc((size_t)MP*64*2);
  half_t* XC16 = (half_t*)alloc((size_t)MP*256*2);
  unsigned short* AGh = (unsigned short*)alloc((size_t)MP*256*2);
  unsigned short* AGl = (unsigned short*)alloc((size_t)MP*256*2);
  float* XC2 = (float*)alloc((size_t)MP*256*4);
  // transposed split weights
  unsigned short* T1h = (unsigned short*)alloc(128*128*2); unsigned short* T1l = (unsigned short*)alloc(128*128*2);
  unsigned short* T2h = (unsigned short*)alloc(128*128*2); unsigned short* T2l = (unsigned short*)alloc(128*128*2);
  unsigned short* T3h = (unsigned short*)alloc(128*128*2); unsigned short* T3l = (unsigned short*)alloc(128*128*2);
  unsigned short* T4h = (unsigned short*)alloc(128*128*2); unsigned short* T4l = (unsigned short*)alloc(128*128*2);
  unsigned short* T5h = (unsigned short*)alloc(64*128*2);  unsigned short* T5l = (unsigned short*)alloc(64*128*2);
  unsigned short* T6h = (unsigned short*)alloc(64*128*2);  unsigned short* T6l = (unsigned short*)alloc(64*128*2);
  unsigned short* T7h = (unsigned short*)alloc(256*256*2); unsigned short* T7l = (unsigned short*)alloc(256*256*2);
  unsigned short* T8h = (unsigned short*)alloc(256*256*2); unsigned short* T8l = (unsigned short*)alloc(256*256*2);
  // CSR (both graphs)
  int*  PTR  = (int*)alloc((size_t)2*(NN+1)*4);
  int*  PTR1 = PTR;
  int*  PTR2 = PTR + (NN+1);
  int2* ESW1 = (int2*)alloc((size_t)EE*8);
  int2* ESW2 = (int2*)alloc((size_t)EE*8);
  int*  CNT  = (int*)alloc((size_t)2*NN*4);
  int*  CUR  = (int*)alloc((size_t)2*NN*4);
  int*  BSUM = (int*)alloc((size_t)2*SCB*4);
  float* EMBS = (float*)alloc((size_t)BB*256*4);
  float* EMB  = (float*)alloc((size_t)BB*256*4);
  float* S2B  = (float*)alloc((size_t)BB*128*4);

  const int* src1 = ei;  const int* dst1 = ei + EE;
  const int* src2 = dei; const int* dst2 = dei + EE;
  const int ebx = NSLICE * ((EE+255)/256);   // XCD-sliced grid

  // CSR build (both graphs, XCD-sliced scatter)
  hipMemsetAsync(CNT, 0, (size_t)2*NN*4, stream);
  count2x_kernel<<<ebx,256,0,stream>>>(dst1, dst2, CNT);
  scan_local_kernel<<<dim3(SCB,2),256,0,stream>>>(CNT, PTR, BSUM);
  scan_bsum_kernel<<<2,256,0,stream>>>(BSUM, PTR);
  scan_add_kernel<<<dim3(SCB,2),256,0,stream>>>(PTR, BSUM, CUR);
  fill2x_kernel<<<ebx,256,0,stream>>>(src1,dst1,ea, src2,dst2,dea, CUR, ESW1, ESW2);

  // fp16 activations
  tohalf_kernel<true ><<<(NN*16+255)/256,256,0,stream>>>(x,  XM16, NN*16);
  tohalf_kernel<false><<<(NN*8 +255)/256,256,0,stream>>>(dx, DX16, NN*8);

  // weight prep: one fused launch (T8 = c1_Wroot + skip_W)
  {
    TS8 a;
    int base = 0;
    auto put = [&](int idx, const float* W, const float* add, unsigned short* oh, unsigned short* ol, int K, int N){
      a.t[idx] = TS{W, add, oh, ol, K, N, base}; base += K*N;
    };
    put(0, g1_Wr,  nullptr, T1h,T1l, 128,128);
    put(1, g1_Wrt, nullptr, T2h,T2l, 128,128);
    put(2, g2_Wr,  nullptr, T3h,T3l, 128,128);
    put(3, g2_Wrt, nullptr, T4h,T4l, 128,128);
    put(4, d1_Wr,  nullptr, T5h,T5l, 64,128);
    put(5, d1_Wrt, nullptr, T6h,T6l, 64,128);
    put(6, c1_Wr,  nullptr, T7h,T7l, 256,256);
    put(7, c1_Wrt, skip_W,  T8h,T8l, 256,256);
    a.total = base;
    tsplit8_kernel<<<(a.total+255)/256,256,0,stream>>>(a);
  }

  const int GB = (NN+127)/128;   // 391

  // ---- g1 ----
  gather_kernel<128><<<(NN*16+255)/256,256,0,stream>>>(XM16,128, PTR1,ESW1, AGh,AGl,128);
  mfma_gemm_kernel<true><<<dim3(GB,1),256,0,stream>>>(AGh,AGl,128, T1h,T1l, XM16,128, T2h,T2l,
                                                      g1_br, nullptr, nullptr, F116, 128, 0);
  // ---- g2 ----
  gather_kernel<128><<<(NN*16+255)/256,256,0,stream>>>(F116,128, PTR1,ESW1, AGh,AGl,128);
  mfma_gemm_kernel<true><<<dim3(GB,1),256,0,stream>>>(AGh,AGl,128, T3h,T3l, F116,128, T4h,T4l,
                                                      g2_br, nullptr, nullptr, XC16, 256, 0);
  // ---- duration branch -> XC cols 128..255 ----
  gather_kernel<64><<<(NN*8+255)/256,256,0,stream>>>(DX16,64, PTR2,ESW2, AGh,AGl,64);
  mfma_gemm_kernel<true><<<dim3(GB,1),256,0,stream>>>(AGh,AGl,64, T5h,T5l, DX16,64, T6h,T6l,
                                                      d1_br, nullptr, nullptr, XC16, 256, 128);
  // ---- c1 + folded skip ----
  gather_kernel<256><<<(NN*32+255)/256,256,0,stream>>>(XC16,256, PTR1,ESW1, AGh,AGl,256);
  mfma_gemm_kernel<false><<<dim3(GB,2),256,0,stream>>>(AGh,AGl,256, T7h,T7l, XC16,256, T8h,T8l,
                                                       c1_br, skip_b, XC2, nullptr, 256, 0);
  // ---- pool (two-phase) ----
  hipMemsetAsync(EMBS, 0, (size_t)BB*256*4, stream);
  pool_partial_kernel<<<GB,256,0,stream>>>(XC2, batch, EMBS);
  pool_final_kernel<<<BB,256,0,stream>>>(EMBS, batch, EMB);
  // ---- seq / head ----
  seq_kernel<<<BB,256,0,stream>>>(seq, fc1_W, fc1_b, fc2_W, fc2_b, S2B);
  head_kernel<<<BB,256,0,stream>>>(EMB, S2B, fcc_W, fcc_b, cls_W, cls_b, out);
}